// Round 1
// baseline (806.041 us; speedup 1.0000x reference)
//
#include <hip/hip_runtime.h>

#define N_NODES 100000
#define N_EDGES 50000
#define NNZ     800000
#define C       256

// bucketed scatter parameters: bucket = contiguous key range so bucket base
// offsets come directly from the CSR offsets (no extra histogram).
#define SH_E 6                                        // 64 edges / bucket
#define SH_N 7                                        // 128 nodes / bucket
#define NB_E ((N_EDGES + (1 << SH_E) - 1) >> SH_E)    // 782
#define NB_N ((N_NODES + (1 << SH_N) - 1) >> SH_N)    // 782

typedef short  bf16x8 __attribute__((ext_vector_type(8)));
typedef float  f32x4  __attribute__((ext_vector_type(4)));

static __device__ __forceinline__ unsigned short f2bf(float f) {
    unsigned int u = __float_as_uint(f);
    u += 0x7FFF + ((u >> 16) & 1);   // round-to-nearest-even
    return (unsigned short)(u >> 16);
}
static __device__ __forceinline__ float bf2f(unsigned short u) {
    return __uint_as_float(((unsigned int)u) << 16);
}

// ---------------- conversions ----------------

__global__ void x0_to_bf16(const float* __restrict__ x0, unsigned short* __restrict__ x0b) {
    size_t i = (size_t)blockIdx.x * blockDim.x + threadIdx.x;   // float4 index
    float4 v = ((const float4*)x0)[i];
    ushort4 o;
    o.x = f2bf(v.x); o.y = f2bf(v.y); o.z = f2bf(v.z); o.w = f2bf(v.w);
    ((ushort4*)x0b)[i] = o;
}

// ---------------- CSR construction ----------------

__global__ void hist_kernel(const int* __restrict__ node_idx,
                            const int* __restrict__ edge_idx,
                            int* __restrict__ cnt_n, int* __restrict__ cnt_e) {
    int j = blockIdx.x * blockDim.x + threadIdx.x;
    atomicAdd(&cnt_n[node_idx[j]], 1);
    atomicAdd(&cnt_e[edge_idx[j]], 1);
}

// pass 1: per-block (1024-elem) sums. n divisible by 4; grid covers ceil(n/1024).
__global__ void scan_partials(const int* __restrict__ cnt, int* __restrict__ partials, int n) {
    int tid = threadIdx.x, lane = tid & 63, wid = tid >> 6;
    int base = blockIdx.x * 1024 + tid * 4;
    int s = 0;
    if (base < n) { int4 v = *(const int4*)(cnt + base); s = v.x + v.y + v.z + v.w; }
#pragma unroll
    for (int o = 1; o < 64; o <<= 1) s += __shfl_down(s, o, 64);
    __shared__ int ws[4];
    if (lane == 0) ws[wid] = s;
    __syncthreads();
    if (tid == 0) partials[blockIdx.x] = ws[0] + ws[1] + ws[2] + ws[3];
}

// pass 2: single 128-thread block, exclusive scan of partials (nb <= 98) in place.
// Also writes off[n] = total (known: NNZ).
__global__ void scan_small(int* __restrict__ partials, int nb, int* __restrict__ off_last, int total) {
    int tid = threadIdx.x, lane = tid & 63, wid = tid >> 6;
    int v = (tid < nb) ? partials[tid] : 0;
    int incl = v;
#pragma unroll
    for (int s = 1; s < 64; s <<= 1) { int u = __shfl_up(incl, s, 64); if (lane >= s) incl += u; }
    __shared__ int wsum[2];
    if (lane == 63) wsum[wid] = incl;
    __syncthreads();
    int excl = incl - v + (wid == 1 ? wsum[0] : 0);
    if (tid < nb) partials[tid] = excl;
    if (tid == 0) *off_last = total;
}

// pass 3: full exclusive scan using block partial base.
__global__ void scan_final(const int* __restrict__ cnt, const int* __restrict__ partials,
                           int* __restrict__ off, int n) {
    int tid = threadIdx.x, lane = tid & 63, wid = tid >> 6;
    int base = blockIdx.x * 1024 + tid * 4;
    int v0 = 0, v1 = 0, v2 = 0, v3 = 0;
    if (base < n) { int4 v = *(const int4*)(cnt + base); v0 = v.x; v1 = v.y; v2 = v.z; v3 = v.w; }
    int tsum = v0 + v1 + v2 + v3;
    int incl = tsum;
#pragma unroll
    for (int s = 1; s < 64; s <<= 1) { int u = __shfl_up(incl, s, 64); if (lane >= s) incl += u; }
    __shared__ int ws[4], wexcl[4];
    if (lane == 63) ws[wid] = incl;
    __syncthreads();
    if (tid == 0) { int c = 0; for (int i = 0; i < 4; i++) { wexcl[i] = c; c += ws[i]; } }
    __syncthreads();
    if (base < n) {
        int b = partials[blockIdx.x] + wexcl[wid] + (incl - tsum);
        off[base]     = b;
        off[base + 1] = b + v0;
        off[base + 2] = b + v0 + v1;
        off[base + 3] = b + v0 + v1 + v2;
    }
}

// ---------------- permutation build: bucketed two-pass scatter ----------------
// Replaces the old build_perm (107 MB of scattered dword writebacks, 135 us).
// Phase B: append packed (value<<SH | key_low) u32 records to per-bucket tails
//          (bucket = contiguous key range, base offsets read from off[]).
// Phase C: one block per bucket re-scatters within the bucket's contiguous
//          position window (~4 KB) -> writes stay L2-resident, ~1 writeback/line.

__global__ void init_bcur(const int* __restrict__ off_e, const int* __restrict__ off_n,
                          int* __restrict__ bcur_e, int* __restrict__ bcur_n) {
    int b = blockIdx.x * blockDim.x + threadIdx.x;
    if (b < NB_E) bcur_e[b] = off_e[b << SH_E];
    if (b < NB_N) bcur_n[b] = off_n[b << SH_N];
}

__global__ void bin_pairs(const int* __restrict__ node_idx,
                          const int* __restrict__ edge_idx,
                          int* __restrict__ bcur_e, int* __restrict__ bcur_n,
                          unsigned int* __restrict__ tmp_e, unsigned int* __restrict__ tmp_n) {
    int j = blockIdx.x * blockDim.x + threadIdx.x;
    int ni = node_idx[j], ei = edge_idx[j];
    // perm_e record: ni (17b) << 6 | ei low 6 bits = 23 bits
    int pe = atomicAdd(&bcur_e[ei >> SH_E], 1);
    tmp_e[pe] = ((unsigned int)ni << SH_E) | (unsigned int)(ei & ((1 << SH_E) - 1));
    // perm_n record: ei (16b) << 7 | ni low 7 bits = 23 bits
    int pn = atomicAdd(&bcur_n[ni >> SH_N], 1);
    tmp_n[pn] = ((unsigned int)ei << SH_N) | (unsigned int)(ni & ((1 << SH_N) - 1));
}

__global__ void scatter_bucket_e(const unsigned int* __restrict__ tmp_e,
                                 const int* __restrict__ off_e,
                                 int* __restrict__ cur_e, int* __restrict__ perm_e) {
    int b = blockIdx.x;
    int start = off_e[b << SH_E];
    int hi = (b + 1) << SH_E;
    int end = off_e[hi < N_EDGES ? hi : N_EDGES];
    for (int k = start + threadIdx.x; k < end; k += blockDim.x) {
        unsigned int u = tmp_e[k];
        int ei = (b << SH_E) | (int)(u & ((1 << SH_E) - 1));
        int pos = atomicAdd(&cur_e[ei], 1);
        perm_e[pos] = (int)(u >> SH_E);
    }
}

__global__ void scatter_bucket_n(const unsigned int* __restrict__ tmp_n,
                                 const int* __restrict__ off_n,
                                 int* __restrict__ cur_n, int* __restrict__ perm_n) {
    int b = blockIdx.x;
    int start = off_n[b << SH_N];
    int hi = (b + 1) << SH_N;
    int end = off_n[hi < N_NODES ? hi : N_NODES];
    for (int k = start + threadIdx.x; k < end; k += blockDim.x) {
        unsigned int u = tmp_n[k];
        int ni = (b << SH_N) | (int)(u & ((1 << SH_N) - 1));
        int pos = atomicAdd(&cur_n[ni], 1);
        perm_n[pos] = (int)(u >> SH_N);
    }
}

// ---------------- segment-sum pulls ----------------

// x1[e] = sum x0b rows; writes fp32 x1 (output) and bf16 x1b (for pull_node).
// One wave per edge; lane covers 4 channels.
__global__ void pull_edge(const unsigned short* __restrict__ x0b,
                          const int* __restrict__ off, const int* __restrict__ perm,
                          float* __restrict__ x1, unsigned short* __restrict__ x1b) {
    int e = blockIdx.x * 4 + (threadIdx.x >> 6);
    int lane = threadIdx.x & 63;
    int s0 = off[e], s1 = off[e + 1];
    float a0 = 0, a1 = 0, a2 = 0, a3 = 0;
    float b0 = 0, b1 = 0, b2 = 0, b3 = 0;
    int k = s0;
    for (; k + 2 <= s1; k += 2) {
        int r0 = perm[k], r1 = perm[k + 1];
        ushort4 u0 = *(const ushort4*)(x0b + (size_t)r0 * C + lane * 4);
        ushort4 u1 = *(const ushort4*)(x0b + (size_t)r1 * C + lane * 4);
        a0 += bf2f(u0.x); a1 += bf2f(u0.y); a2 += bf2f(u0.z); a3 += bf2f(u0.w);
        b0 += bf2f(u1.x); b1 += bf2f(u1.y); b2 += bf2f(u1.z); b3 += bf2f(u1.w);
    }
    if (k < s1) {
        int r0 = perm[k];
        ushort4 u0 = *(const ushort4*)(x0b + (size_t)r0 * C + lane * 4);
        a0 += bf2f(u0.x); a1 += bf2f(u0.y); a2 += bf2f(u0.z); a3 += bf2f(u0.w);
    }
    a0 += b0; a1 += b1; a2 += b2; a3 += b3;
    *(float4*)(x1 + (size_t)e * C + lane * 4) = make_float4(a0, a1, a2, a3);
    ushort4 o; o.x = f2bf(a0); o.y = f2bf(a1); o.z = f2bf(a2); o.w = f2bf(a3);
    *(ushort4*)(x1b + (size_t)e * C + lane * 4) = o;
}

// xm[n] = bf16( x0[n] + sum x1b rows )
__global__ void pull_node(const float* __restrict__ x0, const unsigned short* __restrict__ x1b,
                          const int* __restrict__ off, const int* __restrict__ perm,
                          unsigned short* __restrict__ xm) {
    int n = blockIdx.x * 4 + (threadIdx.x >> 6);
    int lane = threadIdx.x & 63;
    int s0 = off[n], s1 = off[n + 1];
    const float4 x = *(const float4*)(x0 + (size_t)n * C + lane * 4);
    float a0 = x.x, a1 = x.y, a2 = x.z, a3 = x.w;
    float b0 = 0, b1 = 0, b2 = 0, b3 = 0;
    int k = s0;
    for (; k + 2 <= s1; k += 2) {
        int r0 = perm[k], r1 = perm[k + 1];
        ushort4 u0 = *(const ushort4*)(x1b + (size_t)r0 * C + lane * 4);
        ushort4 u1 = *(const ushort4*)(x1b + (size_t)r1 * C + lane * 4);
        a0 += bf2f(u0.x); a1 += bf2f(u0.y); a2 += bf2f(u0.z); a3 += bf2f(u0.w);
        b0 += bf2f(u1.x); b1 += bf2f(u1.y); b2 += bf2f(u1.z); b3 += bf2f(u1.w);
    }
    if (k < s1) {
        int r0 = perm[k];
        ushort4 u0 = *(const ushort4*)(x1b + (size_t)r0 * C + lane * 4);
        a0 += bf2f(u0.x); a1 += bf2f(u0.y); a2 += bf2f(u0.z); a3 += bf2f(u0.w);
    }
    a0 += b0; a1 += b1; a2 += b2; a3 += b3;
    ushort4 o; o.x = f2bf(a0); o.y = f2bf(a1); o.z = f2bf(a2); o.w = f2bf(a3);
    *(ushort4*)(xm + (size_t)n * C + lane * 4) = o;
}

// ---------------- MFMA GEMM v2: W-half staged in 64 KB LDS ----------------
// Block = 512 threads (8 waves), covers 128 rows x 128 cols. grid = 782 row-tiles x 2 halves.
// LDS holds pre-swizzled B-fragments: Bs[((t*8+s)*64+l)*8 + j] = W[colbase+16t+(l&15)][32s+8(l>>4)+j]
// so the compute loop is one ds_read_b128 per (t,s) at lane-consecutive 16B addresses.
__global__ __launch_bounds__(512) void mfma_gemm2(const unsigned short* __restrict__ xm,
                                                  const float* __restrict__ W,
                                                  const float* __restrict__ bias,
                                                  float* __restrict__ out) {
    __shared__ unsigned short Bs[8 * 8 * 64 * 8];   // 65536 B
    const int rt = blockIdx.x >> 1;
    const int colbase = (blockIdx.x & 1) * 128;
    const int tid = threadIdx.x;

    // stage + convert W half (fp32 -> bf16), 4096 x 16B entries, 8 per thread
    for (int i = tid; i < 4096; i += 512) {
        int t = i >> 9, s = (i >> 6) & 7, l = i & 63;
        int m = l & 15, q = l >> 4;
        const float* src = W + (size_t)(colbase + 16 * t + m) * C + 32 * s + 8 * q;
        float4 f0 = *(const float4*)(src);
        float4 f1 = *(const float4*)(src + 4);
        unsigned short* d = Bs + (size_t)i * 8;
        d[0] = f2bf(f0.x); d[1] = f2bf(f0.y); d[2] = f2bf(f0.z); d[3] = f2bf(f0.w);
        d[4] = f2bf(f1.x); d[5] = f2bf(f1.y); d[6] = f2bf(f1.z); d[7] = f2bf(f1.w);
    }

    const int w = tid >> 6, lane = tid & 63;
    const int m = lane & 15, q = lane >> 4;
    const int row = rt * 128 + w * 16 + m;
    const int arow = row < N_NODES ? row : N_NODES - 1;   // clamp tail (stores guarded)

    // preload all 8 A-frags (independent 16B loads, one drain)
    bf16x8 a[8];
    const unsigned short* ap = xm + (size_t)arow * C + q * 8;
#pragma unroll
    for (int s = 0; s < 8; s++) a[s] = *(const bf16x8*)(ap + 32 * s);

    __syncthreads();

    f32x4 acc[8];
#pragma unroll
    for (int t = 0; t < 8; t++) acc[t] = (f32x4){0.f, 0.f, 0.f, 0.f};

#pragma unroll
    for (int s = 0; s < 8; s++) {
#pragma unroll
        for (int t = 0; t < 8; t++) {
            bf16x8 b = *(const bf16x8*)(Bs + ((t * 8 + s) * 64 + lane) * 8);
            acc[t] = __builtin_amdgcn_mfma_f32_16x16x32_bf16(a[s], b, acc[t], 0, 0, 0);
        }
    }

    const int r0 = rt * 128 + w * 16 + q * 4;
#pragma unroll
    for (int t = 0; t < 8; t++) {
        float bv = bias[colbase + t * 16 + m];
#pragma unroll
        for (int r = 0; r < 4; r++) {
            int rr = r0 + r;
            if (rr < N_NODES)
                out[(size_t)rr * C + colbase + t * 16 + m] = acc[t][r] + bv;
        }
    }
}

// ---------------- fallback (round-1 path, used only if ws too small) --------

__global__ void init_kernel(const float* __restrict__ x0, float* __restrict__ out) {
    long long i = (long long)blockIdx.x * blockDim.x + threadIdx.x;
    const long long n_node4 = (long long)N_NODES * C / 4;
    const long long n_tot4  = (long long)(N_NODES + N_EDGES) * C / 4;
    float4* o4 = (float4*)out;
    if (i < n_node4)      o4[i] = ((const float4*)x0)[i];
    else if (i < n_tot4)  o4[i] = make_float4(0.f, 0.f, 0.f, 0.f);
}

__global__ void scatter_add_kernel(const float* __restrict__ src,
                                   const int* __restrict__ src_idx,
                                   const int* __restrict__ dst_idx,
                                   float* __restrict__ dst) {
    int j    = blockIdx.x * (blockDim.x >> 6) + (threadIdx.x >> 6);
    int lane = threadIdx.x & 63;
    if (j >= NNZ) return;
    int s = src_idx[j];
    int d = dst_idx[j];
    const float4 v = *(const float4*)(src + (long long)s * C + lane * 4);
    float* dp = dst + (long long)d * C + lane * 4;
    atomicAdd(dp + 0, v.x); atomicAdd(dp + 1, v.y);
    atomicAdd(dp + 2, v.z); atomicAdd(dp + 3, v.w);
}

__global__ void gin_gemm_kernel(const float* __restrict__ W,
                                const float* __restrict__ b,
                                float* __restrict__ out) {
    int n = blockIdx.x;
    int t = threadIdx.x;
    __shared__ float xs[C];
    float* row = out + (long long)n * C;
    xs[t] = row[t];
    __syncthreads();
    float acc = b[t];
    const float* wrow = W + t * C;
#pragma unroll 8
    for (int k = 0; k < C; k += 4) {
        float4 xv = *(const float4*)(xs + k);
        float4 wv = *(const float4*)(wrow + k);
        acc = fmaf(xv.x, wv.x, acc); acc = fmaf(xv.y, wv.y, acc);
        acc = fmaf(xv.z, wv.z, acc); acc = fmaf(xv.w, wv.w, acc);
    }
    row[t] = acc;
}

// ---------------------------------------------------------------------------

extern "C" void kernel_launch(void* const* d_in, const int* in_sizes, int n_in,
                              void* d_out, int out_size, void* d_ws, size_t ws_size,
                              hipStream_t stream) {
    const float* x0       = (const float*)d_in[0];
    const int*   node_idx = (const int*)d_in[1];
    const int*   edge_idx = (const int*)d_in[2];
    const float* W        = (const float*)d_in[3];
    const float* b        = (const float*)d_in[4];
    float* out = (float*)d_out;
    float* x1  = out + (size_t)N_NODES * C;   // output 1

    char* p = (char*)d_ws;
    size_t used = 0;
    auto alloc = [&](size_t bytes) {
        char* r = p + used;
        used += (bytes + 255) & ~(size_t)255;
        return r;
    };
    int* off_e  = (int*)alloc((N_EDGES + 1) * 4);
    int* off_n  = (int*)alloc((N_NODES + 1) * 4);
    int* cur_e  = (int*)alloc(N_EDGES * 4);
    int* cur_n  = (int*)alloc(N_NODES * 4);
    int* cnt_e  = (int*)alloc(N_EDGES * 4);
    int* cnt_n  = (int*)alloc(N_NODES * 4);
    int* part_e = (int*)alloc(128 * 4);
    int* part_n = (int*)alloc(128 * 4);
    int* bcur_e = (int*)alloc(NB_E * 4);
    int* bcur_n = (int*)alloc(NB_N * 4);
    int* perm_e = (int*)alloc((size_t)NNZ * 4);
    int* perm_n = (int*)alloc((size_t)NNZ * 4);
    unsigned short* x0b = (unsigned short*)alloc((size_t)N_NODES * C * 2);
    unsigned short* x1b = (unsigned short*)alloc((size_t)N_EDGES * C * 2);
    unsigned short* xm  = (unsigned short*)alloc((size_t)N_NODES * C * 2);

    if (ws_size < used) {
        long long tot4 = (long long)(N_NODES + N_EDGES) * C / 4;
        init_kernel<<<(int)((tot4 + 255) / 256), 256, 0, stream>>>(x0, out);
        int grid = NNZ / 4;
        scatter_add_kernel<<<grid, 256, 0, stream>>>(x0, node_idx, edge_idx, x1);
        scatter_add_kernel<<<grid, 256, 0, stream>>>(x1, edge_idx, node_idx, out);
        gin_gemm_kernel<<<N_NODES, 256, 0, stream>>>(W, b, out);
        return;
    }

    hipMemsetAsync(cnt_e, 0, N_EDGES * 4, stream);
    hipMemsetAsync(cnt_n, 0, N_NODES * 4, stream);

    // x0 -> bf16 (for gathers)
    x0_to_bf16<<<N_NODES * C / 4 / 256, 256, 0, stream>>>(x0, x0b);

    // histogram
    hist_kernel<<<NNZ / 256, 256, 0, stream>>>(node_idx, edge_idx, cnt_n, cnt_e);

    // hierarchical exclusive scans
    const int nb_e = (N_EDGES + 1023) / 1024;   // 49
    const int nb_n = (N_NODES + 1023) / 1024;   // 98
    scan_partials<<<nb_e, 256, 0, stream>>>(cnt_e, part_e, N_EDGES);
    scan_small<<<1, 128, 0, stream>>>(part_e, nb_e, off_e + N_EDGES, NNZ);
    scan_final<<<nb_e, 256, 0, stream>>>(cnt_e, part_e, off_e, N_EDGES);
    scan_partials<<<nb_n, 256, 0, stream>>>(cnt_n, part_n, N_NODES);
    scan_small<<<1, 128, 0, stream>>>(part_n, nb_n, off_n + N_NODES, NNZ);
    scan_final<<<nb_n, 256, 0, stream>>>(cnt_n, part_n, off_n, N_NODES);

    // cursors for final in-bucket scatter
    hipMemcpyAsync(cur_e, off_e, N_EDGES * 4, hipMemcpyDeviceToDevice, stream);
    hipMemcpyAsync(cur_n, off_n, N_NODES * 4, hipMemcpyDeviceToDevice, stream);

    // bucket tails from CSR offsets (bucket = contiguous key range)
    init_bcur<<<(NB_E > NB_N ? NB_E : NB_N + 255) / 256 + 1, 256, 0, stream>>>(off_e, off_n, bcur_e, bcur_n);

    // permutations via bucketed two-pass scatter.
    // tmp arrays alias x1b/xm: both are dead until pull_edge/pull_node, which
    // run strictly after the scatter_bucket kernels consumed tmp (same stream).
    unsigned int* tmp_e = (unsigned int*)x1b;
    unsigned int* tmp_n = (unsigned int*)xm;
    bin_pairs<<<NNZ / 256, 256, 0, stream>>>(node_idx, edge_idx, bcur_e, bcur_n, tmp_e, tmp_n);
    scatter_bucket_e<<<NB_E, 256, 0, stream>>>(tmp_e, off_e, cur_e, perm_e);
    scatter_bucket_n<<<NB_N, 256, 0, stream>>>(tmp_n, off_n, cur_n, perm_n);

    // pulls
    pull_edge<<<N_EDGES / 4, 256, 0, stream>>>(x0b, off_e, perm_e, x1, x1b);
    pull_node<<<N_NODES / 4, 256, 0, stream>>>(x0, x1b, off_n, perm_n, xm);

    // GEMM: out0 = xm @ W^T + b
    const int row_tiles = (N_NODES + 127) / 128;   // 782
    mfma_gemm2<<<row_tiles * 2, 512, 0, stream>>>(xm, W, b, out);
}

// Round 2
// 541.707 us; speedup vs baseline: 1.4880x; 1.4880x over previous
//
#include <hip/hip_runtime.h>

#define N_NODES 100000
#define N_EDGES 50000
#define NNZ     800000
#define C       256

// coarse-bucket counting sort: bucket = contiguous key range so bucket base
// offsets come directly from the CSR offsets (no extra histogram).
#define SHC_E 8                                        // 256 edges / bucket
#define SHC_N 9                                        // 512 nodes / bucket
#define NBC_E ((N_EDGES + (1 << SHC_E) - 1) >> SHC_E)  // 196
#define NBC_N ((N_NODES + (1 << SHC_N) - 1) >> SHC_N)  // 196
#define CHUNK 4096
#define NCHUNK ((NNZ + CHUNK - 1) / CHUNK)             // 196

typedef short  bf16x8 __attribute__((ext_vector_type(8)));
typedef float  f32x4  __attribute__((ext_vector_type(4)));

static __device__ __forceinline__ unsigned short f2bf(float f) {
    unsigned int u = __float_as_uint(f);
    u += 0x7FFF + ((u >> 16) & 1);   // round-to-nearest-even
    return (unsigned short)(u >> 16);
}
static __device__ __forceinline__ float bf2f(unsigned short u) {
    return __uint_as_float(((unsigned int)u) << 16);
}

// ---------------- conversions ----------------

__global__ void x0_to_bf16(const float* __restrict__ x0, unsigned short* __restrict__ x0b) {
    size_t i = (size_t)blockIdx.x * blockDim.x + threadIdx.x;   // float4 index
    float4 v = ((const float4*)x0)[i];
    ushort4 o;
    o.x = f2bf(v.x); o.y = f2bf(v.y); o.z = f2bf(v.z); o.w = f2bf(v.w);
    ((ushort4*)x0b)[i] = o;
}

// ---------------- CSR construction ----------------

__global__ void hist_kernel(const int* __restrict__ node_idx,
                            const int* __restrict__ edge_idx,
                            int* __restrict__ cnt_n, int* __restrict__ cnt_e) {
    int j = blockIdx.x * blockDim.x + threadIdx.x;
    atomicAdd(&cnt_n[node_idx[j]], 1);
    atomicAdd(&cnt_e[edge_idx[j]], 1);
}

// pass 1: per-block (1024-elem) sums. n divisible by 4; grid covers ceil(n/1024).
__global__ void scan_partials(const int* __restrict__ cnt, int* __restrict__ partials, int n) {
    int tid = threadIdx.x, lane = tid & 63, wid = tid >> 6;
    int base = blockIdx.x * 1024 + tid * 4;
    int s = 0;
    if (base < n) { int4 v = *(const int4*)(cnt + base); s = v.x + v.y + v.z + v.w; }
#pragma unroll
    for (int o = 1; o < 64; o <<= 1) s += __shfl_down(s, o, 64);
    __shared__ int ws[4];
    if (lane == 0) ws[wid] = s;
    __syncthreads();
    if (tid == 0) partials[blockIdx.x] = ws[0] + ws[1] + ws[2] + ws[3];
}

// pass 2: single 128-thread block, exclusive scan of partials (nb <= 98) in place.
// Also writes off[n] = total (known: NNZ).
__global__ void scan_small(int* __restrict__ partials, int nb, int* __restrict__ off_last, int total) {
    int tid = threadIdx.x, lane = tid & 63, wid = tid >> 6;
    int v = (tid < nb) ? partials[tid] : 0;
    int incl = v;
#pragma unroll
    for (int s = 1; s < 64; s <<= 1) { int u = __shfl_up(incl, s, 64); if (lane >= s) incl += u; }
    __shared__ int wsum[2];
    if (lane == 63) wsum[wid] = incl;
    __syncthreads();
    int excl = incl - v + (wid == 1 ? wsum[0] : 0);
    if (tid < nb) partials[tid] = excl;
    if (tid == 0) *off_last = total;
}

// pass 3: full exclusive scan using block partial base.
__global__ void scan_final(const int* __restrict__ cnt, const int* __restrict__ partials,
                           int* __restrict__ off, int n) {
    int tid = threadIdx.x, lane = tid & 63, wid = tid >> 6;
    int base = blockIdx.x * 1024 + tid * 4;
    int v0 = 0, v1 = 0, v2 = 0, v3 = 0;
    if (base < n) { int4 v = *(const int4*)(cnt + base); v0 = v.x; v1 = v.y; v2 = v.z; v3 = v.w; }
    int tsum = v0 + v1 + v2 + v3;
    int incl = tsum;
#pragma unroll
    for (int s = 1; s < 64; s <<= 1) { int u = __shfl_up(incl, s, 64); if (lane >= s) incl += u; }
    __shared__ int ws[4], wexcl[4];
    if (lane == 63) ws[wid] = incl;
    __syncthreads();
    if (tid == 0) { int c = 0; for (int i = 0; i < 4; i++) { wexcl[i] = c; c += ws[i]; } }
    __syncthreads();
    if (base < n) {
        int b = partials[blockIdx.x] + wexcl[wid] + (incl - tsum);
        off[base]     = b;
        off[base + 1] = b + v0;
        off[base + 2] = b + v0 + v1;
        off[base + 3] = b + v0 + v1 + v2;
    }
}

// ---------------- permutation build: deterministic-ish counting sort ----------
// Phase B (bin_coarse): per-block LDS histogram over coarse buckets, ONE global
//   atomic per (block,bucket) to reserve a contiguous region, LDS-cursor scatter
//   into it. No per-entry global atomics; each tmp line written by ~one block.
// Phase C (scatter_fine): one block per coarse bucket; CSR cursors staged in
//   LDS; scatter with LDS atomics into the bucket's contiguous perm window
//   (~16 KB, XCD-private, L2-resident).

__global__ void init_gcur(const int* __restrict__ off_e, const int* __restrict__ off_n,
                          int* __restrict__ gcur_e, int* __restrict__ gcur_n) {
    int b = blockIdx.x * blockDim.x + threadIdx.x;
    if (b < NBC_E) gcur_e[b] = off_e[b << SHC_E];
    if (b < NBC_N) gcur_n[b] = off_n[b << SHC_N];
}

__global__ __launch_bounds__(256) void bin_coarse(const int* __restrict__ node_idx,
                                                  const int* __restrict__ edge_idx,
                                                  int* __restrict__ gcur_e, int* __restrict__ gcur_n,
                                                  unsigned int* __restrict__ tmp_e,
                                                  unsigned int* __restrict__ tmp_n) {
    __shared__ int hist_e[NBC_E], hist_n[NBC_N];
    __shared__ int base_e[NBC_E], base_n[NBC_N];
    const int tid = threadIdx.x;
    const int start = blockIdx.x * CHUNK;
    const int end = (start + CHUNK < NNZ) ? start + CHUNK : NNZ;

    for (int i = tid; i < NBC_E; i += 256) hist_e[i] = 0;
    for (int i = tid; i < NBC_N; i += 256) hist_n[i] = 0;
    __syncthreads();

    // pass 1: local histogram (LDS atomics)
    for (int k = start + tid; k < end; k += 256) {
        atomicAdd(&hist_e[edge_idx[k] >> SHC_E], 1);
        atomicAdd(&hist_n[node_idx[k] >> SHC_N], 1);
    }
    __syncthreads();

    // reserve contiguous regions: one global atomic per (block,bucket)
    for (int i = tid; i < NBC_E; i += 256) {
        int c = hist_e[i];
        base_e[i] = c ? atomicAdd(&gcur_e[i], c) : 0;
        hist_e[i] = 0;
    }
    for (int i = tid; i < NBC_N; i += 256) {
        int c = hist_n[i];
        base_n[i] = c ? atomicAdd(&gcur_n[i], c) : 0;
        hist_n[i] = 0;
    }
    __syncthreads();

    // pass 2: scatter into reserved regions (hist reused as LDS cursor)
    for (int k = start + tid; k < end; k += 256) {
        int ni = node_idx[k], ei = edge_idx[k];
        int be = ei >> SHC_E;
        int pe = base_e[be] + atomicAdd(&hist_e[be], 1);
        tmp_e[pe] = ((unsigned int)ni << SHC_E) | (unsigned int)(ei & ((1 << SHC_E) - 1));
        int bn = ni >> SHC_N;
        int pn = base_n[bn] + atomicAdd(&hist_n[bn], 1);
        tmp_n[pn] = ((unsigned int)ei << SHC_N) | (unsigned int)(ni & ((1 << SHC_N) - 1));
    }
}

__global__ __launch_bounds__(256) void scatter_fine_e(const unsigned int* __restrict__ tmp_e,
                                                      const int* __restrict__ off_e,
                                                      int* __restrict__ perm_e) {
    __shared__ int cur[1 << SHC_E];   // 256 absolute CSR cursors
    const int b = blockIdx.x, tid = threadIdx.x;
    const int kbase = b << SHC_E;
    int key = kbase + tid;
    cur[tid] = off_e[key < N_EDGES ? key : N_EDGES];
    const int start = off_e[kbase];
    int endk = kbase + (1 << SHC_E);
    const int end = off_e[endk < N_EDGES ? endk : N_EDGES];
    __syncthreads();
    for (int k = start + tid; k < end; k += 256) {
        unsigned int u = tmp_e[k];
        int pos = atomicAdd(&cur[u & ((1 << SHC_E) - 1)], 1);
        perm_e[pos] = (int)(u >> SHC_E);
    }
}

__global__ __launch_bounds__(256) void scatter_fine_n(const unsigned int* __restrict__ tmp_n,
                                                      const int* __restrict__ off_n,
                                                      int* __restrict__ perm_n) {
    __shared__ int cur[1 << SHC_N];   // 512 absolute CSR cursors
    const int b = blockIdx.x, tid = threadIdx.x;
    const int kbase = b << SHC_N;
    for (int t = tid; t < (1 << SHC_N); t += 256) {
        int key = kbase + t;
        cur[t] = off_n[key < N_NODES ? key : N_NODES];
    }
    const int start = off_n[kbase];
    int endk = kbase + (1 << SHC_N);
    const int end = off_n[endk < N_NODES ? endk : N_NODES];
    __syncthreads();
    for (int k = start + tid; k < end; k += 256) {
        unsigned int u = tmp_n[k];
        int pos = atomicAdd(&cur[u & ((1 << SHC_N) - 1)], 1);
        perm_n[pos] = (int)(u >> SHC_N);
    }
}

// ---------------- segment-sum pulls ----------------

// x1[e] = sum x0b rows; writes fp32 x1 (output) and bf16 x1b (for pull_node).
// One wave per edge; lane covers 4 channels.
__global__ void pull_edge(const unsigned short* __restrict__ x0b,
                          const int* __restrict__ off, const int* __restrict__ perm,
                          float* __restrict__ x1, unsigned short* __restrict__ x1b) {
    int e = blockIdx.x * 4 + (threadIdx.x >> 6);
    int lane = threadIdx.x & 63;
    int s0 = off[e], s1 = off[e + 1];
    float a0 = 0, a1 = 0, a2 = 0, a3 = 0;
    float b0 = 0, b1 = 0, b2 = 0, b3 = 0;
    int k = s0;
    for (; k + 2 <= s1; k += 2) {
        int r0 = perm[k], r1 = perm[k + 1];
        ushort4 u0 = *(const ushort4*)(x0b + (size_t)r0 * C + lane * 4);
        ushort4 u1 = *(const ushort4*)(x0b + (size_t)r1 * C + lane * 4);
        a0 += bf2f(u0.x); a1 += bf2f(u0.y); a2 += bf2f(u0.z); a3 += bf2f(u0.w);
        b0 += bf2f(u1.x); b1 += bf2f(u1.y); b2 += bf2f(u1.z); b3 += bf2f(u1.w);
    }
    if (k < s1) {
        int r0 = perm[k];
        ushort4 u0 = *(const ushort4*)(x0b + (size_t)r0 * C + lane * 4);
        a0 += bf2f(u0.x); a1 += bf2f(u0.y); a2 += bf2f(u0.z); a3 += bf2f(u0.w);
    }
    a0 += b0; a1 += b1; a2 += b2; a3 += b3;
    *(float4*)(x1 + (size_t)e * C + lane * 4) = make_float4(a0, a1, a2, a3);
    ushort4 o; o.x = f2bf(a0); o.y = f2bf(a1); o.z = f2bf(a2); o.w = f2bf(a3);
    *(ushort4*)(x1b + (size_t)e * C + lane * 4) = o;
}

// xm[n] = bf16( x0[n] + sum x1b rows )
__global__ void pull_node(const float* __restrict__ x0, const unsigned short* __restrict__ x1b,
                          const int* __restrict__ off, const int* __restrict__ perm,
                          unsigned short* __restrict__ xm) {
    int n = blockIdx.x * 4 + (threadIdx.x >> 6);
    int lane = threadIdx.x & 63;
    int s0 = off[n], s1 = off[n + 1];
    const float4 x = *(const float4*)(x0 + (size_t)n * C + lane * 4);
    float a0 = x.x, a1 = x.y, a2 = x.z, a3 = x.w;
    float b0 = 0, b1 = 0, b2 = 0, b3 = 0;
    int k = s0;
    for (; k + 2 <= s1; k += 2) {
        int r0 = perm[k], r1 = perm[k + 1];
        ushort4 u0 = *(const ushort4*)(x1b + (size_t)r0 * C + lane * 4);
        ushort4 u1 = *(const ushort4*)(x1b + (size_t)r1 * C + lane * 4);
        a0 += bf2f(u0.x); a1 += bf2f(u0.y); a2 += bf2f(u0.z); a3 += bf2f(u0.w);
        b0 += bf2f(u1.x); b1 += bf2f(u1.y); b2 += bf2f(u1.z); b3 += bf2f(u1.w);
    }
    if (k < s1) {
        int r0 = perm[k];
        ushort4 u0 = *(const ushort4*)(x1b + (size_t)r0 * C + lane * 4);
        a0 += bf2f(u0.x); a1 += bf2f(u0.y); a2 += bf2f(u0.z); a3 += bf2f(u0.w);
    }
    a0 += b0; a1 += b1; a2 += b2; a3 += b3;
    ushort4 o; o.x = f2bf(a0); o.y = f2bf(a1); o.z = f2bf(a2); o.w = f2bf(a3);
    *(ushort4*)(xm + (size_t)n * C + lane * 4) = o;
}

// ---------------- MFMA GEMM v2: W-half staged in 64 KB LDS ----------------
// Block = 512 threads (8 waves), covers 128 rows x 128 cols. grid = 782 row-tiles x 2 halves.
// LDS holds pre-swizzled B-fragments: Bs[((t*8+s)*64+l)*8 + j] = W[colbase+16t+(l&15)][32s+8(l>>4)+j]
// so the compute loop is one ds_read_b128 per (t,s) at lane-consecutive 16B addresses.
__global__ __launch_bounds__(512) void mfma_gemm2(const unsigned short* __restrict__ xm,
                                                  const float* __restrict__ W,
                                                  const float* __restrict__ bias,
                                                  float* __restrict__ out) {
    __shared__ unsigned short Bs[8 * 8 * 64 * 8];   // 65536 B
    const int rt = blockIdx.x >> 1;
    const int colbase = (blockIdx.x & 1) * 128;
    const int tid = threadIdx.x;

    // stage + convert W half (fp32 -> bf16), 4096 x 16B entries, 8 per thread
    for (int i = tid; i < 4096; i += 512) {
        int t = i >> 9, s = (i >> 6) & 7, l = i & 63;
        int m = l & 15, q = l >> 4;
        const float* src = W + (size_t)(colbase + 16 * t + m) * C + 32 * s + 8 * q;
        float4 f0 = *(const float4*)(src);
        float4 f1 = *(const float4*)(src + 4);
        unsigned short* d = Bs + (size_t)i * 8;
        d[0] = f2bf(f0.x); d[1] = f2bf(f0.y); d[2] = f2bf(f0.z); d[3] = f2bf(f0.w);
        d[4] = f2bf(f1.x); d[5] = f2bf(f1.y); d[6] = f2bf(f1.z); d[7] = f2bf(f1.w);
    }

    const int w = tid >> 6, lane = tid & 63;
    const int m = lane & 15, q = lane >> 4;
    const int row = rt * 128 + w * 16 + m;
    const int arow = row < N_NODES ? row : N_NODES - 1;   // clamp tail (stores guarded)

    // preload all 8 A-frags (independent 16B loads, one drain)
    bf16x8 a[8];
    const unsigned short* ap = xm + (size_t)arow * C + q * 8;
#pragma unroll
    for (int s = 0; s < 8; s++) a[s] = *(const bf16x8*)(ap + 32 * s);

    __syncthreads();

    f32x4 acc[8];
#pragma unroll
    for (int t = 0; t < 8; t++) acc[t] = (f32x4){0.f, 0.f, 0.f, 0.f};

#pragma unroll
    for (int s = 0; s < 8; s++) {
#pragma unroll
        for (int t = 0; t < 8; t++) {
            bf16x8 b = *(const bf16x8*)(Bs + ((t * 8 + s) * 64 + lane) * 8);
            acc[t] = __builtin_amdgcn_mfma_f32_16x16x32_bf16(a[s], b, acc[t], 0, 0, 0);
        }
    }

    const int r0 = rt * 128 + w * 16 + q * 4;
#pragma unroll
    for (int t = 0; t < 8; t++) {
        float bv = bias[colbase + t * 16 + m];
#pragma unroll
        for (int r = 0; r < 4; r++) {
            int rr = r0 + r;
            if (rr < N_NODES)
                out[(size_t)rr * C + colbase + t * 16 + m] = acc[t][r] + bv;
        }
    }
}

// ---------------- fallback (round-1 path, used only if ws too small) --------

__global__ void init_kernel(const float* __restrict__ x0, float* __restrict__ out) {
    long long i = (long long)blockIdx.x * blockDim.x + threadIdx.x;
    const long long n_node4 = (long long)N_NODES * C / 4;
    const long long n_tot4  = (long long)(N_NODES + N_EDGES) * C / 4;
    float4* o4 = (float4*)out;
    if (i < n_node4)      o4[i] = ((const float4*)x0)[i];
    else if (i < n_tot4)  o4[i] = make_float4(0.f, 0.f, 0.f, 0.f);
}

__global__ void scatter_add_kernel(const float* __restrict__ src,
                                   const int* __restrict__ src_idx,
                                   const int* __restrict__ dst_idx,
                                   float* __restrict__ dst) {
    int j    = blockIdx.x * (blockDim.x >> 6) + (threadIdx.x >> 6);
    int lane = threadIdx.x & 63;
    if (j >= NNZ) return;
    int s = src_idx[j];
    int d = dst_idx[j];
    const float4 v = *(const float4*)(src + (long long)s * C + lane * 4);
    float* dp = dst + (long long)d * C + lane * 4;
    atomicAdd(dp + 0, v.x); atomicAdd(dp + 1, v.y);
    atomicAdd(dp + 2, v.z); atomicAdd(dp + 3, v.w);
}

__global__ void gin_gemm_kernel(const float* __restrict__ W,
                                const float* __restrict__ b,
                                float* __restrict__ out) {
    int n = blockIdx.x;
    int t = threadIdx.x;
    __shared__ float xs[C];
    float* row = out + (long long)n * C;
    xs[t] = row[t];
    __syncthreads();
    float acc = b[t];
    const float* wrow = W + t * C;
#pragma unroll 8
    for (int k = 0; k < C; k += 4) {
        float4 xv = *(const float4*)(xs + k);
        float4 wv = *(const float4*)(wrow + k);
        acc = fmaf(xv.x, wv.x, acc); acc = fmaf(xv.y, wv.y, acc);
        acc = fmaf(xv.z, wv.z, acc); acc = fmaf(xv.w, wv.w, acc);
    }
    row[t] = acc;
}

// ---------------------------------------------------------------------------

extern "C" void kernel_launch(void* const* d_in, const int* in_sizes, int n_in,
                              void* d_out, int out_size, void* d_ws, size_t ws_size,
                              hipStream_t stream) {
    const float* x0       = (const float*)d_in[0];
    const int*   node_idx = (const int*)d_in[1];
    const int*   edge_idx = (const int*)d_in[2];
    const float* W        = (const float*)d_in[3];
    const float* b        = (const float*)d_in[4];
    float* out = (float*)d_out;
    float* x1  = out + (size_t)N_NODES * C;   // output 1

    char* p = (char*)d_ws;
    size_t used = 0;
    auto alloc = [&](size_t bytes) {
        char* r = p + used;
        used += (bytes + 255) & ~(size_t)255;
        return r;
    };
    int* off_e  = (int*)alloc((N_EDGES + 1) * 4);
    int* off_n  = (int*)alloc((N_NODES + 1) * 4);
    int* cnt_e  = (int*)alloc(N_EDGES * 4);
    int* cnt_n  = (int*)alloc(N_NODES * 4);
    int* part_e = (int*)alloc(128 * 4);
    int* part_n = (int*)alloc(128 * 4);
    int* gcur_e = (int*)alloc(NBC_E * 4);
    int* gcur_n = (int*)alloc(NBC_N * 4);
    int* perm_e = (int*)alloc((size_t)NNZ * 4);
    int* perm_n = (int*)alloc((size_t)NNZ * 4);
    unsigned short* x0b = (unsigned short*)alloc((size_t)N_NODES * C * 2);
    unsigned short* x1b = (unsigned short*)alloc((size_t)N_EDGES * C * 2);
    unsigned short* xm  = (unsigned short*)alloc((size_t)N_NODES * C * 2);

    if (ws_size < used) {
        long long tot4 = (long long)(N_NODES + N_EDGES) * C / 4;
        init_kernel<<<(int)((tot4 + 255) / 256), 256, 0, stream>>>(x0, out);
        int grid = NNZ / 4;
        scatter_add_kernel<<<grid, 256, 0, stream>>>(x0, node_idx, edge_idx, x1);
        scatter_add_kernel<<<grid, 256, 0, stream>>>(x1, edge_idx, node_idx, out);
        gin_gemm_kernel<<<N_NODES, 256, 0, stream>>>(W, b, out);
        return;
    }

    hipMemsetAsync(cnt_e, 0, N_EDGES * 4, stream);
    hipMemsetAsync(cnt_n, 0, N_NODES * 4, stream);

    // x0 -> bf16 (for gathers)
    x0_to_bf16<<<N_NODES * C / 4 / 256, 256, 0, stream>>>(x0, x0b);

    // histogram
    hist_kernel<<<NNZ / 256, 256, 0, stream>>>(node_idx, edge_idx, cnt_n, cnt_e);

    // hierarchical exclusive scans
    const int nb_e = (N_EDGES + 1023) / 1024;   // 49
    const int nb_n = (N_NODES + 1023) / 1024;   // 98
    scan_partials<<<nb_e, 256, 0, stream>>>(cnt_e, part_e, N_EDGES);
    scan_small<<<1, 128, 0, stream>>>(part_e, nb_e, off_e + N_EDGES, NNZ);
    scan_final<<<nb_e, 256, 0, stream>>>(cnt_e, part_e, off_e, N_EDGES);
    scan_partials<<<nb_n, 256, 0, stream>>>(cnt_n, part_n, N_NODES);
    scan_small<<<1, 128, 0, stream>>>(part_n, nb_n, off_n + N_NODES, NNZ);
    scan_final<<<nb_n, 256, 0, stream>>>(cnt_n, part_n, off_n, N_NODES);

    // coarse-bucket region cursors from CSR offsets (bucket = contiguous range)
    init_gcur<<<1, 256, 0, stream>>>(off_e, off_n, gcur_e, gcur_n);

    // permutation build: counting-sort partition (no per-entry global atomics).
    // tmp arrays alias x1b/xm: both are dead until pull_edge/pull_node, which
    // run strictly after the scatter_fine kernels consumed tmp (same stream).
    unsigned int* tmp_e = (unsigned int*)x1b;
    unsigned int* tmp_n = (unsigned int*)xm;
    bin_coarse<<<NCHUNK, 256, 0, stream>>>(node_idx, edge_idx, gcur_e, gcur_n, tmp_e, tmp_n);
    scatter_fine_e<<<NBC_E, 256, 0, stream>>>(tmp_e, off_e, perm_e);
    scatter_fine_n<<<NBC_N, 256, 0, stream>>>(tmp_n, off_n, perm_n);

    // pulls
    pull_edge<<<N_EDGES / 4, 256, 0, stream>>>(x0b, off_e, perm_e, x1, x1b);
    pull_node<<<N_NODES / 4, 256, 0, stream>>>(x0, x1b, off_n, perm_n, xm);

    // GEMM: out0 = xm @ W^T + b
    const int row_tiles = (N_NODES + 127) / 128;   // 782
    mfma_gemm2<<<row_tiles * 2, 512, 0, stream>>>(xm, W, b, out);
}

// Round 3
// 499.656 us; speedup vs baseline: 1.6132x; 1.0842x over previous
//
#include <hip/hip_runtime.h>

#define N_NODES 100000
#define N_EDGES 50000
#define NNZ     800000
#define C       256

// coarse-bucket counting sort: bucket = contiguous key range so bucket base
// offsets come directly from the CSR offsets (no extra histogram).
#define SHC_E 8                                        // 256 edges / bucket
#define SHC_N 9                                        // 512 nodes / bucket
#define NBC_E ((N_EDGES + (1 << SHC_E) - 1) >> SHC_E)  // 196
#define NBC_N ((N_NODES + (1 << SHC_N) - 1) >> SHC_N)  // 196
#define CHUNK 4096
#define NCHUNK ((NNZ + CHUNK - 1) / CHUNK)             // 196

#define NBLK_E ((N_EDGES + 1023) / 1024)               // 49
#define NBLK_N ((N_NODES + 1023) / 1024)               // 98
#define CONV_BLOCKS (N_NODES * C / 4 / 256)            // 25600
#define HIST_BLOCKS (NNZ / 256)                        // 3125

typedef short  bf16x8 __attribute__((ext_vector_type(8)));
typedef float  f32x4  __attribute__((ext_vector_type(4)));

static __device__ __forceinline__ unsigned short f2bf(float f) {
    unsigned int u = __float_as_uint(f);
    u += 0x7FFF + ((u >> 16) & 1);   // round-to-nearest-even
    return (unsigned short)(u >> 16);
}
static __device__ __forceinline__ float bf2f(unsigned short u) {
    return __uint_as_float(((unsigned int)u) << 16);
}

// ---------------- fused x0->bf16 conversion + degree histogram ----------------

__global__ void convert_hist(const float* __restrict__ x0, unsigned short* __restrict__ x0b,
                             const int* __restrict__ node_idx, const int* __restrict__ edge_idx,
                             int* __restrict__ cnt_n, int* __restrict__ cnt_e) {
    int bid = blockIdx.x;
    if (bid < CONV_BLOCKS) {
        size_t i = (size_t)bid * 256 + threadIdx.x;   // float4 index
        float4 v = ((const float4*)x0)[i];
        ushort4 o;
        o.x = f2bf(v.x); o.y = f2bf(v.y); o.z = f2bf(v.z); o.w = f2bf(v.w);
        ((ushort4*)x0b)[i] = o;
    } else {
        int j = (bid - CONV_BLOCKS) * 256 + threadIdx.x;
        atomicAdd(&cnt_n[node_idx[j]], 1);
        atomicAdd(&cnt_e[edge_idx[j]], 1);
    }
}

// ---------------- W -> bf16, pre-swizzled to the GEMM's LDS layout ------------
// Wb[h][(t*8+s)*64+l][j] = bf16(W[h*128+16t+(l&15)][32s+8(l>>4)+j]); h = col half.

__global__ void prep_w(const float* __restrict__ W, unsigned short* __restrict__ Wb) {
    int idx = blockIdx.x * 256 + threadIdx.x;   // 0..8191
    int h = idx >> 12, i = idx & 4095;
    int t = i >> 9, s = (i >> 6) & 7, l = i & 63;
    int m = l & 15, q = l >> 4;
    const float* src = W + (size_t)(h * 128 + 16 * t + m) * C + 32 * s + 8 * q;
    float4 f0 = *(const float4*)(src);
    float4 f1 = *(const float4*)(src + 4);
    unsigned short* d = Wb + (size_t)idx * 8;
    d[0] = f2bf(f0.x); d[1] = f2bf(f0.y); d[2] = f2bf(f0.z); d[3] = f2bf(f0.w);
    d[4] = f2bf(f1.x); d[5] = f2bf(f1.y); d[6] = f2bf(f1.z); d[7] = f2bf(f1.w);
}

// ---------------- CSR construction (merged e/n scan passes) ----------------

// pass 1: per-block (1024-elem) sums over cnt_e (blocks [0,NBLK_E)) and cnt_n.
__global__ void scan_partials2(const int* __restrict__ cnt_e, const int* __restrict__ cnt_n,
                               int* __restrict__ part_e, int* __restrict__ part_n) {
    bool isE = blockIdx.x < NBLK_E;
    const int* cnt = isE ? cnt_e : cnt_n;
    int* partials = isE ? part_e : part_n;
    int n = isE ? N_EDGES : N_NODES;
    int bid = isE ? blockIdx.x : blockIdx.x - NBLK_E;
    int tid = threadIdx.x, lane = tid & 63, wid = tid >> 6;
    int base = bid * 1024 + tid * 4;
    int s = 0;
    if (base < n) { int4 v = *(const int4*)(cnt + base); s = v.x + v.y + v.z + v.w; }
#pragma unroll
    for (int o = 1; o < 64; o <<= 1) s += __shfl_down(s, o, 64);
    __shared__ int ws[4];
    if (lane == 0) ws[wid] = s;
    __syncthreads();
    if (tid == 0) partials[bid] = ws[0] + ws[1] + ws[2] + ws[3];
}

// pass 2: block 0 scans part_e, block 1 scans part_n (nb <= 98, 128 threads).
__global__ void scan_small2(int* __restrict__ part_e, int* __restrict__ part_n,
                            int* __restrict__ off_e_last, int* __restrict__ off_n_last) {
    int* partials = (blockIdx.x == 0) ? part_e : part_n;
    int nb = (blockIdx.x == 0) ? NBLK_E : NBLK_N;
    int* off_last = (blockIdx.x == 0) ? off_e_last : off_n_last;
    int tid = threadIdx.x, lane = tid & 63, wid = tid >> 6;
    int v = (tid < nb) ? partials[tid] : 0;
    int incl = v;
#pragma unroll
    for (int s = 1; s < 64; s <<= 1) { int u = __shfl_up(incl, s, 64); if (lane >= s) incl += u; }
    __shared__ int wsum[2];
    if (lane == 63) wsum[wid] = incl;
    __syncthreads();
    int excl = incl - v + (wid == 1 ? wsum[0] : 0);
    if (tid < nb) partials[tid] = excl;
    if (tid == 0) *off_last = NNZ;
}

// pass 3: full exclusive scan; also emits coarse-bucket base cursors (gcur).
__global__ void scan_final2(const int* __restrict__ cnt_e, const int* __restrict__ cnt_n,
                            const int* __restrict__ part_e, const int* __restrict__ part_n,
                            int* __restrict__ off_e, int* __restrict__ off_n,
                            int* __restrict__ gcur_e, int* __restrict__ gcur_n) {
    bool isE = blockIdx.x < NBLK_E;
    const int* cnt = isE ? cnt_e : cnt_n;
    const int* partials = isE ? part_e : part_n;
    int* off = isE ? off_e : off_n;
    int* gcur = isE ? gcur_e : gcur_n;
    int shc = isE ? SHC_E : SHC_N;
    int n = isE ? N_EDGES : N_NODES;
    int bid = isE ? blockIdx.x : blockIdx.x - NBLK_E;
    int tid = threadIdx.x, lane = tid & 63, wid = tid >> 6;
    int base = bid * 1024 + tid * 4;
    int v0 = 0, v1 = 0, v2 = 0, v3 = 0;
    if (base < n) { int4 v = *(const int4*)(cnt + base); v0 = v.x; v1 = v.y; v2 = v.z; v3 = v.w; }
    int tsum = v0 + v1 + v2 + v3;
    int incl = tsum;
#pragma unroll
    for (int s = 1; s < 64; s <<= 1) { int u = __shfl_up(incl, s, 64); if (lane >= s) incl += u; }
    __shared__ int ws[4], wexcl[4];
    if (lane == 63) ws[wid] = incl;
    __syncthreads();
    if (tid == 0) { int c = 0; for (int i = 0; i < 4; i++) { wexcl[i] = c; c += ws[i]; } }
    __syncthreads();
    if (base < n) {
        int b = partials[bid] + wexcl[wid] + (incl - tsum);
        off[base]     = b;
        off[base + 1] = b + v0;
        off[base + 2] = b + v0 + v1;
        off[base + 3] = b + v0 + v1 + v2;
        if ((base & ((1 << shc) - 1)) == 0) gcur[base >> shc] = b;   // bucket region cursor
    }
}

// ---------------- permutation build: counting-sort partition ----------------
// Phase B (bin_coarse): per-block LDS histogram over coarse buckets, ONE global
//   atomic per (block,bucket) to reserve a contiguous region, LDS-cursor scatter.
// Phase C (scatter_fine): one block per coarse bucket; CSR cursors in LDS;
//   scatter into the bucket's contiguous perm window (L2-resident).

__global__ __launch_bounds__(256) void bin_coarse(const int* __restrict__ node_idx,
                                                  const int* __restrict__ edge_idx,
                                                  int* __restrict__ gcur_e, int* __restrict__ gcur_n,
                                                  unsigned int* __restrict__ tmp_e,
                                                  unsigned int* __restrict__ tmp_n) {
    __shared__ int hist_e[NBC_E], hist_n[NBC_N];
    __shared__ int base_e[NBC_E], base_n[NBC_N];
    const int tid = threadIdx.x;
    const int start = blockIdx.x * CHUNK;
    const int end = (start + CHUNK < NNZ) ? start + CHUNK : NNZ;

    for (int i = tid; i < NBC_E; i += 256) hist_e[i] = 0;
    for (int i = tid; i < NBC_N; i += 256) hist_n[i] = 0;
    __syncthreads();

    for (int k = start + tid; k < end; k += 256) {
        atomicAdd(&hist_e[edge_idx[k] >> SHC_E], 1);
        atomicAdd(&hist_n[node_idx[k] >> SHC_N], 1);
    }
    __syncthreads();

    for (int i = tid; i < NBC_E; i += 256) {
        int c = hist_e[i];
        base_e[i] = c ? atomicAdd(&gcur_e[i], c) : 0;
        hist_e[i] = 0;
    }
    for (int i = tid; i < NBC_N; i += 256) {
        int c = hist_n[i];
        base_n[i] = c ? atomicAdd(&gcur_n[i], c) : 0;
        hist_n[i] = 0;
    }
    __syncthreads();

    for (int k = start + tid; k < end; k += 256) {
        int ni = node_idx[k], ei = edge_idx[k];
        int be = ei >> SHC_E;
        int pe = base_e[be] + atomicAdd(&hist_e[be], 1);
        tmp_e[pe] = ((unsigned int)ni << SHC_E) | (unsigned int)(ei & ((1 << SHC_E) - 1));
        int bn = ni >> SHC_N;
        int pn = base_n[bn] + atomicAdd(&hist_n[bn], 1);
        tmp_n[pn] = ((unsigned int)ei << SHC_N) | (unsigned int)(ni & ((1 << SHC_N) - 1));
    }
}

__global__ __launch_bounds__(256) void scatter_fine(const unsigned int* __restrict__ tmp_e,
                                                    const unsigned int* __restrict__ tmp_n,
                                                    const int* __restrict__ off_e,
                                                    const int* __restrict__ off_n,
                                                    int* __restrict__ perm_e,
                                                    int* __restrict__ perm_n) {
    __shared__ int cur[1 << SHC_N];   // 512 absolute CSR cursors (max of both)
    bool isE = blockIdx.x < NBC_E;
    const unsigned int* tmp = isE ? tmp_e : tmp_n;
    const int* off = isE ? off_e : off_n;
    int* perm = isE ? perm_e : perm_n;
    int b = isE ? blockIdx.x : blockIdx.x - NBC_E;
    int shc = isE ? SHC_E : SHC_N;
    int n = isE ? N_EDGES : N_NODES;
    const int tid = threadIdx.x;
    const int kbase = b << shc;
    const int nk = 1 << shc;
    for (int t = tid; t < nk; t += 256) {
        int key = kbase + t;
        cur[t] = off[key < n ? key : n];
    }
    const int start = off[kbase];
    int endk = kbase + nk;
    const int end = off[endk < n ? endk : n];
    __syncthreads();
    for (int k = start + tid; k < end; k += 256) {
        unsigned int u = tmp[k];
        int pos = atomicAdd(&cur[u & (nk - 1)], 1);
        perm[pos] = (int)(u >> shc);
    }
}

// ---------------- segment-sum pulls (unroll-4: 4 outstanding gathers) --------

__global__ void pull_edge(const unsigned short* __restrict__ x0b,
                          const int* __restrict__ off, const int* __restrict__ perm,
                          float* __restrict__ x1, unsigned short* __restrict__ x1b) {
    int e = blockIdx.x * 4 + (threadIdx.x >> 6);
    int lane = threadIdx.x & 63;
    int s0 = off[e], s1 = off[e + 1];
    float a0 = 0, a1 = 0, a2 = 0, a3 = 0;
    float b0 = 0, b1 = 0, b2 = 0, b3 = 0;
    float c0 = 0, c1 = 0, c2 = 0, c3 = 0;
    float d0 = 0, d1 = 0, d2 = 0, d3 = 0;
    int k = s0;
    for (; k + 4 <= s1; k += 4) {
        int r0 = perm[k], r1 = perm[k + 1], r2 = perm[k + 2], r3 = perm[k + 3];
        ushort4 u0 = *(const ushort4*)(x0b + (size_t)r0 * C + lane * 4);
        ushort4 u1 = *(const ushort4*)(x0b + (size_t)r1 * C + lane * 4);
        ushort4 u2 = *(const ushort4*)(x0b + (size_t)r2 * C + lane * 4);
        ushort4 u3 = *(const ushort4*)(x0b + (size_t)r3 * C + lane * 4);
        a0 += bf2f(u0.x); a1 += bf2f(u0.y); a2 += bf2f(u0.z); a3 += bf2f(u0.w);
        b0 += bf2f(u1.x); b1 += bf2f(u1.y); b2 += bf2f(u1.z); b3 += bf2f(u1.w);
        c0 += bf2f(u2.x); c1 += bf2f(u2.y); c2 += bf2f(u2.z); c3 += bf2f(u2.w);
        d0 += bf2f(u3.x); d1 += bf2f(u3.y); d2 += bf2f(u3.z); d3 += bf2f(u3.w);
    }
    for (; k < s1; k++) {
        int r0 = perm[k];
        ushort4 u0 = *(const ushort4*)(x0b + (size_t)r0 * C + lane * 4);
        a0 += bf2f(u0.x); a1 += bf2f(u0.y); a2 += bf2f(u0.z); a3 += bf2f(u0.w);
    }
    a0 += b0 + c0 + d0; a1 += b1 + c1 + d1; a2 += b2 + c2 + d2; a3 += b3 + c3 + d3;
    f32x4 v = {a0, a1, a2, a3};
    __builtin_nontemporal_store(v, (f32x4*)(x1 + (size_t)e * C + lane * 4));   // pure output
    ushort4 o; o.x = f2bf(a0); o.y = f2bf(a1); o.z = f2bf(a2); o.w = f2bf(a3);
    *(ushort4*)(x1b + (size_t)e * C + lane * 4) = o;
}

__global__ void pull_node(const float* __restrict__ x0, const unsigned short* __restrict__ x1b,
                          const int* __restrict__ off, const int* __restrict__ perm,
                          unsigned short* __restrict__ xm) {
    int n = blockIdx.x * 4 + (threadIdx.x >> 6);
    int lane = threadIdx.x & 63;
    int s0 = off[n], s1 = off[n + 1];
    const float4 x = *(const float4*)(x0 + (size_t)n * C + lane * 4);
    float a0 = x.x, a1 = x.y, a2 = x.z, a3 = x.w;
    float b0 = 0, b1 = 0, b2 = 0, b3 = 0;
    float c0 = 0, c1 = 0, c2 = 0, c3 = 0;
    float d0 = 0, d1 = 0, d2 = 0, d3 = 0;
    int k = s0;
    for (; k + 4 <= s1; k += 4) {
        int r0 = perm[k], r1 = perm[k + 1], r2 = perm[k + 2], r3 = perm[k + 3];
        ushort4 u0 = *(const ushort4*)(x1b + (size_t)r0 * C + lane * 4);
        ushort4 u1 = *(const ushort4*)(x1b + (size_t)r1 * C + lane * 4);
        ushort4 u2 = *(const ushort4*)(x1b + (size_t)r2 * C + lane * 4);
        ushort4 u3 = *(const ushort4*)(x1b + (size_t)r3 * C + lane * 4);
        a0 += bf2f(u0.x); a1 += bf2f(u0.y); a2 += bf2f(u0.z); a3 += bf2f(u0.w);
        b0 += bf2f(u1.x); b1 += bf2f(u1.y); b2 += bf2f(u1.z); b3 += bf2f(u1.w);
        c0 += bf2f(u2.x); c1 += bf2f(u2.y); c2 += bf2f(u2.z); c3 += bf2f(u2.w);
        d0 += bf2f(u3.x); d1 += bf2f(u3.y); d2 += bf2f(u3.z); d3 += bf2f(u3.w);
    }
    for (; k < s1; k++) {
        int r0 = perm[k];
        ushort4 u0 = *(const ushort4*)(x1b + (size_t)r0 * C + lane * 4);
        a0 += bf2f(u0.x); a1 += bf2f(u0.y); a2 += bf2f(u0.z); a3 += bf2f(u0.w);
    }
    a0 += b0 + c0 + d0; a1 += b1 + c1 + d1; a2 += b2 + c2 + d2; a3 += b3 + c3 + d3;
    ushort4 o; o.x = f2bf(a0); o.y = f2bf(a1); o.z = f2bf(a2); o.w = f2bf(a3);
    *(ushort4*)(xm + (size_t)n * C + lane * 4) = o;
}

// ---------------- MFMA GEMM: pre-swizzled bf16 W-half staged in 64 KB LDS ----
// Block = 512 threads (8 waves), covers 128 rows x 128 cols. grid = 782 x 2 halves.
// Staging is a straight 64 KB bf16x8 copy from Wb (already in fragment layout).
__global__ __launch_bounds__(512) void mfma_gemm2(const unsigned short* __restrict__ xm,
                                                  const unsigned short* __restrict__ Wb,
                                                  const float* __restrict__ bias,
                                                  float* __restrict__ out) {
    __shared__ unsigned short Bs[8 * 8 * 64 * 8];   // 65536 B
    const int rt = blockIdx.x >> 1;
    const int colbase = (blockIdx.x & 1) * 128;
    const int tid = threadIdx.x;

    const unsigned short* wsrc = Wb + (size_t)(blockIdx.x & 1) * (4096 * 8);
#pragma unroll
    for (int it = 0; it < 8; it++) {
        int i = it * 512 + tid;
        *(bf16x8*)(Bs + (size_t)i * 8) = *(const bf16x8*)(wsrc + (size_t)i * 8);
    }

    const int w = tid >> 6, lane = tid & 63;
    const int m = lane & 15, q = lane >> 4;
    const int row = rt * 128 + w * 16 + m;
    const int arow = row < N_NODES ? row : N_NODES - 1;   // clamp tail (stores guarded)

    // preload all 8 A-frags (independent 16B loads, one drain)
    bf16x8 a[8];
    const unsigned short* ap = xm + (size_t)arow * C + q * 8;
#pragma unroll
    for (int s = 0; s < 8; s++) a[s] = *(const bf16x8*)(ap + 32 * s);

    __syncthreads();

    f32x4 acc[8];
#pragma unroll
    for (int t = 0; t < 8; t++) acc[t] = (f32x4){0.f, 0.f, 0.f, 0.f};

#pragma unroll
    for (int s = 0; s < 8; s++) {
#pragma unroll
        for (int t = 0; t < 8; t++) {
            bf16x8 b = *(const bf16x8*)(Bs + ((t * 8 + s) * 64 + lane) * 8);
            acc[t] = __builtin_amdgcn_mfma_f32_16x16x32_bf16(a[s], b, acc[t], 0, 0, 0);
        }
    }

    const int r0 = rt * 128 + w * 16 + q * 4;
#pragma unroll
    for (int t = 0; t < 8; t++) {
        float bv = bias[colbase + t * 16 + m];
#pragma unroll
        for (int r = 0; r < 4; r++) {
            int rr = r0 + r;
            if (rr < N_NODES)
                out[(size_t)rr * C + colbase + t * 16 + m] = acc[t][r] + bv;
        }
    }
}

// ---------------- fallback (round-1 path, used only if ws too small) --------

__global__ void init_kernel(const float* __restrict__ x0, float* __restrict__ out) {
    long long i = (long long)blockIdx.x * blockDim.x + threadIdx.x;
    const long long n_node4 = (long long)N_NODES * C / 4;
    const long long n_tot4  = (long long)(N_NODES + N_EDGES) * C / 4;
    float4* o4 = (float4*)out;
    if (i < n_node4)      o4[i] = ((const float4*)x0)[i];
    else if (i < n_tot4)  o4[i] = make_float4(0.f, 0.f, 0.f, 0.f);
}

__global__ void scatter_add_kernel(const float* __restrict__ src,
                                   const int* __restrict__ src_idx,
                                   const int* __restrict__ dst_idx,
                                   float* __restrict__ dst) {
    int j    = blockIdx.x * (blockDim.x >> 6) + (threadIdx.x >> 6);
    int lane = threadIdx.x & 63;
    if (j >= NNZ) return;
    int s = src_idx[j];
    int d = dst_idx[j];
    const float4 v = *(const float4*)(src + (long long)s * C + lane * 4);
    float* dp = dst + (long long)d * C + lane * 4;
    atomicAdd(dp + 0, v.x); atomicAdd(dp + 1, v.y);
    atomicAdd(dp + 2, v.z); atomicAdd(dp + 3, v.w);
}

__global__ void gin_gemm_kernel(const float* __restrict__ W,
                                const float* __restrict__ b,
                                float* __restrict__ out) {
    int n = blockIdx.x;
    int t = threadIdx.x;
    __shared__ float xs[C];
    float* row = out + (long long)n * C;
    xs[t] = row[t];
    __syncthreads();
    float acc = b[t];
    const float* wrow = W + t * C;
#pragma unroll 8
    for (int k = 0; k < C; k += 4) {
        float4 xv = *(const float4*)(xs + k);
        float4 wv = *(const float4*)(wrow + k);
        acc = fmaf(xv.x, wv.x, acc); acc = fmaf(xv.y, wv.y, acc);
        acc = fmaf(xv.z, wv.z, acc); acc = fmaf(xv.w, wv.w, acc);
    }
    row[t] = acc;
}

// ---------------------------------------------------------------------------

extern "C" void kernel_launch(void* const* d_in, const int* in_sizes, int n_in,
                              void* d_out, int out_size, void* d_ws, size_t ws_size,
                              hipStream_t stream) {
    const float* x0       = (const float*)d_in[0];
    const int*   node_idx = (const int*)d_in[1];
    const int*   edge_idx = (const int*)d_in[2];
    const float* W        = (const float*)d_in[3];
    const float* b        = (const float*)d_in[4];
    float* out = (float*)d_out;
    float* x1  = out + (size_t)N_NODES * C;   // output 1

    char* p = (char*)d_ws;
    size_t used = 0;
    auto alloc = [&](size_t bytes) {
        char* r = p + used;
        used += (bytes + 255) & ~(size_t)255;
        return r;
    };
    int* off_e  = (int*)alloc((N_EDGES + 1) * 4);
    int* off_n  = (int*)alloc((N_NODES + 1) * 4);
    int* cnt_e  = (int*)alloc(N_EDGES * 4);     // cnt_e/cnt_n adjacent: single memset
    int* cnt_n  = (int*)alloc(N_NODES * 4);
    int* part_e = (int*)alloc(128 * 4);
    int* part_n = (int*)alloc(128 * 4);
    int* gcur_e = (int*)alloc(NBC_E * 4);
    int* gcur_n = (int*)alloc(NBC_N * 4);
    int* perm_e = (int*)alloc((size_t)NNZ * 4);
    int* perm_n = (int*)alloc((size_t)NNZ * 4);
    unsigned short* Wb  = (unsigned short*)alloc((size_t)2 * 4096 * 8 * 2);
    unsigned short* x0b = (unsigned short*)alloc((size_t)N_NODES * C * 2);
    unsigned short* x1b = (unsigned short*)alloc((size_t)N_EDGES * C * 2);
    unsigned short* xm  = (unsigned short*)alloc((size_t)N_NODES * C * 2);

    if (ws_size < used) {
        long long tot4 = (long long)(N_NODES + N_EDGES) * C / 4;
        init_kernel<<<(int)((tot4 + 255) / 256), 256, 0, stream>>>(x0, out);
        int grid = NNZ / 4;
        scatter_add_kernel<<<grid, 256, 0, stream>>>(x0, node_idx, edge_idx, x1);
        scatter_add_kernel<<<grid, 256, 0, stream>>>(x1, edge_idx, node_idx, out);
        gin_gemm_kernel<<<N_NODES, 256, 0, stream>>>(W, b, out);
        return;
    }

    // single memset over the adjacent cnt_e | cnt_n region
    hipMemsetAsync(cnt_e, 0, (size_t)((char*)cnt_n - (char*)cnt_e) + (size_t)N_NODES * 4, stream);

    // fused x0->bf16 conversion + degree histogram
    convert_hist<<<CONV_BLOCKS + HIST_BLOCKS, 256, 0, stream>>>(x0, x0b, node_idx, edge_idx, cnt_n, cnt_e);

    // W -> pre-swizzled bf16 (once)
    prep_w<<<32, 256, 0, stream>>>(W, Wb);

    // hierarchical exclusive scans (e and n merged per pass); scan_final also
    // emits the coarse-bucket region cursors.
    scan_partials2<<<NBLK_E + NBLK_N, 256, 0, stream>>>(cnt_e, cnt_n, part_e, part_n);
    scan_small2<<<2, 128, 0, stream>>>(part_e, part_n, off_e + N_EDGES, off_n + N_NODES);
    scan_final2<<<NBLK_E + NBLK_N, 256, 0, stream>>>(cnt_e, cnt_n, part_e, part_n,
                                                     off_e, off_n, gcur_e, gcur_n);

    // permutation build: counting-sort partition (no per-entry global atomics).
    // tmp arrays alias x1b/xm: both are dead until pull_edge/pull_node, which
    // run strictly after scatter_fine consumed tmp (same stream).
    unsigned int* tmp_e = (unsigned int*)x1b;
    unsigned int* tmp_n = (unsigned int*)xm;
    bin_coarse<<<NCHUNK, 256, 0, stream>>>(node_idx, edge_idx, gcur_e, gcur_n, tmp_e, tmp_n);
    scatter_fine<<<NBC_E + NBC_N, 256, 0, stream>>>(tmp_e, tmp_n, off_e, off_n, perm_e, perm_n);

    // pulls
    pull_edge<<<N_EDGES / 4, 256, 0, stream>>>(x0b, off_e, perm_e, x1, x1b);
    pull_node<<<N_NODES / 4, 256, 0, stream>>>(x0, x1b, off_n, perm_n, xm);

    // GEMM: out0 = xm @ W^T + b
    const int row_tiles = (N_NODES + 127) / 128;   // 782
    mfma_gemm2<<<row_tiles * 2, 512, 0, stream>>>(xm, Wb, b, out);
}

// Round 4
// 452.628 us; speedup vs baseline: 1.7808x; 1.1039x over previous
//
#include <hip/hip_runtime.h>

#define N_NODES 100000
#define N_EDGES 50000
#define NNZ     800000
#define C       256

// coarse-bucket counting sort: bucket = contiguous key range.
#define SHC_E 8                                        // 256 edges / bucket
#define SHC_N 9                                        // 512 nodes / bucket
#define NBC_E ((N_EDGES + (1 << SHC_E) - 1) >> SHC_E)  // 196
#define NBC_N ((N_NODES + (1 << SHC_N) - 1) >> SHC_N)  // 196
#define CHUNK 4096
#define NCHUNK ((NNZ + CHUNK - 1) / CHUNK)             // 196

#define CONV_BLOCKS (N_NODES * C / 4 / 256)            // 25600

typedef short  bf16x8 __attribute__((ext_vector_type(8)));
typedef float  f32x4  __attribute__((ext_vector_type(4)));

static __device__ __forceinline__ unsigned short f2bf(float f) {
    unsigned int u = __float_as_uint(f);
    u += 0x7FFF + ((u >> 16) & 1);   // round-to-nearest-even
    return (unsigned short)(u >> 16);
}
static __device__ __forceinline__ float bf2f(unsigned short u) {
    return __uint_as_float(((unsigned int)u) << 16);
}

// ------------- fused x0->bf16 conversion + COARSE degree histogram -----------
// Histogram blocks build a per-chunk LDS histogram over the 196 coarse buckets
// and flush once per (block,bin): ~77k global atomics total (was 1.6M random).

__global__ void convert_hist(const float* __restrict__ x0, unsigned short* __restrict__ x0b,
                             const int* __restrict__ node_idx, const int* __restrict__ edge_idx,
                             int* __restrict__ gcnt_e, int* __restrict__ gcnt_n) {
    int bid = blockIdx.x;
    if (bid < CONV_BLOCKS) {
        size_t i = (size_t)bid * 256 + threadIdx.x;   // float4 index
        float4 v = ((const float4*)x0)[i];
        ushort4 o;
        o.x = f2bf(v.x); o.y = f2bf(v.y); o.z = f2bf(v.z); o.w = f2bf(v.w);
        ((ushort4*)x0b)[i] = o;
    } else {
        __shared__ int he[NBC_E], hn[NBC_N];
        const int tid = threadIdx.x;
        for (int i = tid; i < NBC_E; i += 256) he[i] = 0;
        for (int i = tid; i < NBC_N; i += 256) hn[i] = 0;
        __syncthreads();
        const int start = (bid - CONV_BLOCKS) * CHUNK;
        const int end = (start + CHUNK < NNZ) ? start + CHUNK : NNZ;
        for (int k = start + tid; k < end; k += 256) {
            atomicAdd(&he[edge_idx[k] >> SHC_E], 1);
            atomicAdd(&hn[node_idx[k] >> SHC_N], 1);
        }
        __syncthreads();
        for (int i = tid; i < NBC_E; i += 256) if (he[i]) atomicAdd(&gcnt_e[i], he[i]);
        for (int i = tid; i < NBC_N; i += 256) if (hn[i]) atomicAdd(&gcnt_n[i], hn[i]);
    }
}

// ---------------- W -> bf16, pre-swizzled to the GEMM's LDS layout ------------

__global__ void prep_w(const float* __restrict__ W, unsigned short* __restrict__ Wb) {
    int idx = blockIdx.x * 256 + threadIdx.x;   // 0..8191
    int h = idx >> 12, i = idx & 4095;
    int t = i >> 9, s = (i >> 6) & 7, l = i & 63;
    int m = l & 15, q = l >> 4;
    const float* src = W + (size_t)(h * 128 + 16 * t + m) * C + 32 * s + 8 * q;
    float4 f0 = *(const float4*)(src);
    float4 f1 = *(const float4*)(src + 4);
    unsigned short* d = Wb + (size_t)idx * 8;
    d[0] = f2bf(f0.x); d[1] = f2bf(f0.y); d[2] = f2bf(f0.z); d[3] = f2bf(f0.w);
    d[4] = f2bf(f1.x); d[5] = f2bf(f1.y); d[6] = f2bf(f1.z); d[7] = f2bf(f1.w);
}

// ------------- coarse exclusive scan: gcnt -> gbase (regions) + gcur ---------
// block 0 = edges, block 1 = nodes; nb = 196, 256 threads (4 waves).

__global__ void coarse_scan(const int* __restrict__ gcnt_e, const int* __restrict__ gcnt_n,
                            int* __restrict__ gbase_e, int* __restrict__ gbase_n,
                            int* __restrict__ gcur_e, int* __restrict__ gcur_n) {
    const int* gcnt = (blockIdx.x == 0) ? gcnt_e : gcnt_n;
    int* gbase = (blockIdx.x == 0) ? gbase_e : gbase_n;
    int* gcur  = (blockIdx.x == 0) ? gcur_e : gcur_n;
    const int nb = (blockIdx.x == 0) ? NBC_E : NBC_N;
    int tid = threadIdx.x, lane = tid & 63, wid = tid >> 6;
    int v = (tid < nb) ? gcnt[tid] : 0;
    int incl = v;
#pragma unroll
    for (int s = 1; s < 64; s <<= 1) { int u = __shfl_up(incl, s, 64); if (lane >= s) incl += u; }
    __shared__ int wsum[4];
    if (lane == 63) wsum[wid] = incl;
    __syncthreads();
    int add = 0;
    for (int i = 0; i < wid; i++) add += wsum[i];
    int excl = add + incl - v;
    if (tid <= nb) gbase[tid] = excl;        // gbase[nb] = NNZ
    if (tid < nb)  gcur[tid]  = excl;
}

// ---------------- permutation build: counting-sort partition ----------------
// Phase B (bin_coarse): per-block LDS histogram over coarse buckets, ONE global
//   atomic per (block,bucket) to reserve a contiguous region, LDS-cursor scatter.

__global__ __launch_bounds__(256) void bin_coarse(const int* __restrict__ node_idx,
                                                  const int* __restrict__ edge_idx,
                                                  int* __restrict__ gcur_e, int* __restrict__ gcur_n,
                                                  unsigned int* __restrict__ tmp_e,
                                                  unsigned int* __restrict__ tmp_n) {
    __shared__ int hist_e[NBC_E], hist_n[NBC_N];
    __shared__ int base_e[NBC_E], base_n[NBC_N];
    const int tid = threadIdx.x;
    const int start = blockIdx.x * CHUNK;
    const int end = (start + CHUNK < NNZ) ? start + CHUNK : NNZ;

    for (int i = tid; i < NBC_E; i += 256) hist_e[i] = 0;
    for (int i = tid; i < NBC_N; i += 256) hist_n[i] = 0;
    __syncthreads();

    for (int k = start + tid; k < end; k += 256) {
        atomicAdd(&hist_e[edge_idx[k] >> SHC_E], 1);
        atomicAdd(&hist_n[node_idx[k] >> SHC_N], 1);
    }
    __syncthreads();

    for (int i = tid; i < NBC_E; i += 256) {
        int c = hist_e[i];
        base_e[i] = c ? atomicAdd(&gcur_e[i], c) : 0;
        hist_e[i] = 0;
    }
    for (int i = tid; i < NBC_N; i += 256) {
        int c = hist_n[i];
        base_n[i] = c ? atomicAdd(&gcur_n[i], c) : 0;
        hist_n[i] = 0;
    }
    __syncthreads();

    for (int k = start + tid; k < end; k += 256) {
        int ni = node_idx[k], ei = edge_idx[k];
        int be = ei >> SHC_E;
        int pe = base_e[be] + atomicAdd(&hist_e[be], 1);
        tmp_e[pe] = ((unsigned int)ni << SHC_E) | (unsigned int)(ei & ((1 << SHC_E) - 1));
        int bn = ni >> SHC_N;
        int pn = base_n[bn] + atomicAdd(&hist_n[bn], 1);
        tmp_n[pn] = ((unsigned int)ei << SHC_N) | (unsigned int)(ni & ((1 << SHC_N) - 1));
    }
}

// Phase C (scatter_fine): per coarse bucket — LDS fine histogram of the
// bucket's tmp slice, LDS exclusive scan, writes the off[] slice, then
// scatters perm into the bucket's contiguous L2-resident window.

template <int SHC, int NTOT>
static __device__ __forceinline__ void scatter_fine_body(const unsigned int* __restrict__ tmp,
                                                         const int* __restrict__ gbase,
                                                         int* __restrict__ off,
                                                         int* __restrict__ perm,
                                                         int b, int* hist, int* cur, int* wsum) {
    constexpr int NK = 1 << SHC;
    const int tid = threadIdx.x, lane = tid & 63, wid = tid >> 6;
    const int start = gbase[b], end = gbase[b + 1];
    for (int t = tid; t < NK; t += 256) hist[t] = 0;
    __syncthreads();
    for (int k = start + tid; k < end; k += 256)
        atomicAdd(&hist[tmp[k] & (NK - 1)], 1);
    __syncthreads();
    int v0, v1 = 0, local;
    if constexpr (NK == 512) { v0 = hist[2 * tid]; v1 = hist[2 * tid + 1]; local = v0 + v1; }
    else                     { v0 = hist[tid]; local = v0; }
    int incl = local;
#pragma unroll
    for (int s = 1; s < 64; s <<= 1) { int u = __shfl_up(incl, s, 64); if (lane >= s) incl += u; }
    if (lane == 63) wsum[wid] = incl;
    __syncthreads();
    int add = 0;
    for (int i = 0; i < wid; i++) add += wsum[i];
    int base = start + add + incl - local;   // absolute exclusive position
    const int kbase = b << SHC;
    if constexpr (NK == 512) {
        int key0 = kbase + 2 * tid;
        if (key0 < NTOT)     off[key0] = base;
        if (key0 + 1 < NTOT) off[key0 + 1] = base + v0;
        cur[2 * tid]     = base;
        cur[2 * tid + 1] = base + v0;
    } else {
        int key0 = kbase + tid;
        if (key0 < NTOT) off[key0] = base;
        cur[tid] = base;
    }
    if (b == ((NTOT - 1) >> SHC) && tid == 0) off[NTOT] = end;   // = NNZ
    __syncthreads();
    for (int k = start + tid; k < end; k += 256) {
        unsigned int u = tmp[k];
        int pos = atomicAdd(&cur[u & (NK - 1)], 1);
        perm[pos] = (int)(u >> SHC);
    }
}

__global__ __launch_bounds__(256) void scatter_fine(const unsigned int* __restrict__ tmp_e,
                                                    const unsigned int* __restrict__ tmp_n,
                                                    const int* __restrict__ gbase_e,
                                                    const int* __restrict__ gbase_n,
                                                    int* __restrict__ off_e, int* __restrict__ off_n,
                                                    int* __restrict__ perm_e, int* __restrict__ perm_n) {
    __shared__ int hist[1 << SHC_N], cur[1 << SHC_N], wsum[4];
    if (blockIdx.x < NBC_E)
        scatter_fine_body<SHC_E, N_EDGES>(tmp_e, gbase_e, off_e, perm_e, blockIdx.x, hist, cur, wsum);
    else
        scatter_fine_body<SHC_N, N_NODES>(tmp_n, gbase_n, off_n, perm_n, blockIdx.x - NBC_E, hist, cur, wsum);
}

// ---------------- segment-sum pulls (unroll-4: 4 outstanding gathers) --------

__global__ void pull_edge(const unsigned short* __restrict__ x0b,
                          const int* __restrict__ off, const int* __restrict__ perm,
                          float* __restrict__ x1, unsigned short* __restrict__ x1b) {
    int e = blockIdx.x * 4 + (threadIdx.x >> 6);
    int lane = threadIdx.x & 63;
    int s0 = off[e], s1 = off[e + 1];
    float a0 = 0, a1 = 0, a2 = 0, a3 = 0;
    float b0 = 0, b1 = 0, b2 = 0, b3 = 0;
    float c0 = 0, c1 = 0, c2 = 0, c3 = 0;
    float d0 = 0, d1 = 0, d2 = 0, d3 = 0;
    int k = s0;
    for (; k + 4 <= s1; k += 4) {
        int r0 = perm[k], r1 = perm[k + 1], r2 = perm[k + 2], r3 = perm[k + 3];
        ushort4 u0 = *(const ushort4*)(x0b + (size_t)r0 * C + lane * 4);
        ushort4 u1 = *(const ushort4*)(x0b + (size_t)r1 * C + lane * 4);
        ushort4 u2 = *(const ushort4*)(x0b + (size_t)r2 * C + lane * 4);
        ushort4 u3 = *(const ushort4*)(x0b + (size_t)r3 * C + lane * 4);
        a0 += bf2f(u0.x); a1 += bf2f(u0.y); a2 += bf2f(u0.z); a3 += bf2f(u0.w);
        b0 += bf2f(u1.x); b1 += bf2f(u1.y); b2 += bf2f(u1.z); b3 += bf2f(u1.w);
        c0 += bf2f(u2.x); c1 += bf2f(u2.y); c2 += bf2f(u2.z); c3 += bf2f(u2.w);
        d0 += bf2f(u3.x); d1 += bf2f(u3.y); d2 += bf2f(u3.z); d3 += bf2f(u3.w);
    }
    for (; k < s1; k++) {
        int r0 = perm[k];
        ushort4 u0 = *(const ushort4*)(x0b + (size_t)r0 * C + lane * 4);
        a0 += bf2f(u0.x); a1 += bf2f(u0.y); a2 += bf2f(u0.z); a3 += bf2f(u0.w);
    }
    a0 += b0 + c0 + d0; a1 += b1 + c1 + d1; a2 += b2 + c2 + d2; a3 += b3 + c3 + d3;
    f32x4 v = {a0, a1, a2, a3};
    __builtin_nontemporal_store(v, (f32x4*)(x1 + (size_t)e * C + lane * 4));   // pure output
    ushort4 o; o.x = f2bf(a0); o.y = f2bf(a1); o.z = f2bf(a2); o.w = f2bf(a3);
    *(ushort4*)(x1b + (size_t)e * C + lane * 4) = o;
}

__global__ void pull_node(const float* __restrict__ x0, const unsigned short* __restrict__ x1b,
                          const int* __restrict__ off, const int* __restrict__ perm,
                          unsigned short* __restrict__ xm) {
    int n = blockIdx.x * 4 + (threadIdx.x >> 6);
    int lane = threadIdx.x & 63;
    int s0 = off[n], s1 = off[n + 1];
    const float4 x = *(const float4*)(x0 + (size_t)n * C + lane * 4);
    float a0 = x.x, a1 = x.y, a2 = x.z, a3 = x.w;
    float b0 = 0, b1 = 0, b2 = 0, b3 = 0;
    float c0 = 0, c1 = 0, c2 = 0, c3 = 0;
    float d0 = 0, d1 = 0, d2 = 0, d3 = 0;
    int k = s0;
    for (; k + 4 <= s1; k += 4) {
        int r0 = perm[k], r1 = perm[k + 1], r2 = perm[k + 2], r3 = perm[k + 3];
        ushort4 u0 = *(const ushort4*)(x1b + (size_t)r0 * C + lane * 4);
        ushort4 u1 = *(const ushort4*)(x1b + (size_t)r1 * C + lane * 4);
        ushort4 u2 = *(const ushort4*)(x1b + (size_t)r2 * C + lane * 4);
        ushort4 u3 = *(const ushort4*)(x1b + (size_t)r3 * C + lane * 4);
        a0 += bf2f(u0.x); a1 += bf2f(u0.y); a2 += bf2f(u0.z); a3 += bf2f(u0.w);
        b0 += bf2f(u1.x); b1 += bf2f(u1.y); b2 += bf2f(u1.z); b3 += bf2f(u1.w);
        c0 += bf2f(u2.x); c1 += bf2f(u2.y); c2 += bf2f(u2.z); c3 += bf2f(u2.w);
        d0 += bf2f(u3.x); d1 += bf2f(u3.y); d2 += bf2f(u3.z); d3 += bf2f(u3.w);
    }
    for (; k < s1; k++) {
        int r0 = perm[k];
        ushort4 u0 = *(const ushort4*)(x1b + (size_t)r0 * C + lane * 4);
        a0 += bf2f(u0.x); a1 += bf2f(u0.y); a2 += bf2f(u0.z); a3 += bf2f(u0.w);
    }
    a0 += b0 + c0 + d0; a1 += b1 + c1 + d1; a2 += b2 + c2 + d2; a3 += b3 + c3 + d3;
    ushort4 o; o.x = f2bf(a0); o.y = f2bf(a1); o.z = f2bf(a2); o.w = f2bf(a3);
    *(ushort4*)(xm + (size_t)n * C + lane * 4) = o;
}

// ---------------- MFMA GEMM: pre-swizzled bf16 W-half staged in 64 KB LDS ----

__global__ __launch_bounds__(512) void mfma_gemm2(const unsigned short* __restrict__ xm,
                                                  const unsigned short* __restrict__ Wb,
                                                  const float* __restrict__ bias,
                                                  float* __restrict__ out) {
    __shared__ unsigned short Bs[8 * 8 * 64 * 8];   // 65536 B
    const int rt = blockIdx.x >> 1;
    const int colbase = (blockIdx.x & 1) * 128;
    const int tid = threadIdx.x;

    const unsigned short* wsrc = Wb + (size_t)(blockIdx.x & 1) * (4096 * 8);
#pragma unroll
    for (int it = 0; it < 8; it++) {
        int i = it * 512 + tid;
        *(bf16x8*)(Bs + (size_t)i * 8) = *(const bf16x8*)(wsrc + (size_t)i * 8);
    }

    const int w = tid >> 6, lane = tid & 63;
    const int m = lane & 15, q = lane >> 4;
    const int row = rt * 128 + w * 16 + m;
    const int arow = row < N_NODES ? row : N_NODES - 1;   // clamp tail (stores guarded)

    bf16x8 a[8];
    const unsigned short* ap = xm + (size_t)arow * C + q * 8;
#pragma unroll
    for (int s = 0; s < 8; s++) a[s] = *(const bf16x8*)(ap + 32 * s);

    __syncthreads();

    f32x4 acc[8];
#pragma unroll
    for (int t = 0; t < 8; t++) acc[t] = (f32x4){0.f, 0.f, 0.f, 0.f};

#pragma unroll
    for (int s = 0; s < 8; s++) {
#pragma unroll
        for (int t = 0; t < 8; t++) {
            bf16x8 b = *(const bf16x8*)(Bs + ((t * 8 + s) * 64 + lane) * 8);
            acc[t] = __builtin_amdgcn_mfma_f32_16x16x32_bf16(a[s], b, acc[t], 0, 0, 0);
        }
    }

    const int r0 = rt * 128 + w * 16 + q * 4;
#pragma unroll
    for (int t = 0; t < 8; t++) {
        float bv = bias[colbase + t * 16 + m];
#pragma unroll
        for (int r = 0; r < 4; r++) {
            int rr = r0 + r;
            if (rr < N_NODES)
                out[(size_t)rr * C + colbase + t * 16 + m] = acc[t][r] + bv;
        }
    }
}

// ---------------- fallback (round-1 path, used only if ws too small) --------

__global__ void init_kernel(const float* __restrict__ x0, float* __restrict__ out) {
    long long i = (long long)blockIdx.x * blockDim.x + threadIdx.x;
    const long long n_node4 = (long long)N_NODES * C / 4;
    const long long n_tot4  = (long long)(N_NODES + N_EDGES) * C / 4;
    float4* o4 = (float4*)out;
    if (i < n_node4)      o4[i] = ((const float4*)x0)[i];
    else if (i < n_tot4)  o4[i] = make_float4(0.f, 0.f, 0.f, 0.f);
}

__global__ void scatter_add_kernel(const float* __restrict__ src,
                                   const int* __restrict__ src_idx,
                                   const int* __restrict__ dst_idx,
                                   float* __restrict__ dst) {
    int j    = blockIdx.x * (blockDim.x >> 6) + (threadIdx.x >> 6);
    int lane = threadIdx.x & 63;
    if (j >= NNZ) return;
    int s = src_idx[j];
    int d = dst_idx[j];
    const float4 v = *(const float4*)(src + (long long)s * C + lane * 4);
    float* dp = dst + (long long)d * C + lane * 4;
    atomicAdd(dp + 0, v.x); atomicAdd(dp + 1, v.y);
    atomicAdd(dp + 2, v.z); atomicAdd(dp + 3, v.w);
}

__global__ void gin_gemm_kernel(const float* __restrict__ W,
                                const float* __restrict__ b,
                                float* __restrict__ out) {
    int n = blockIdx.x;
    int t = threadIdx.x;
    __shared__ float xs[C];
    float* row = out + (long long)n * C;
    xs[t] = row[t];
    __syncthreads();
    float acc = b[t];
    const float* wrow = W + t * C;
#pragma unroll 8
    for (int k = 0; k < C; k += 4) {
        float4 xv = *(const float4*)(xs + k);
        float4 wv = *(const float4*)(wrow + k);
        acc = fmaf(xv.x, wv.x, acc); acc = fmaf(xv.y, wv.y, acc);
        acc = fmaf(xv.z, wv.z, acc); acc = fmaf(xv.w, wv.w, acc);
    }
    row[t] = acc;
}

// ---------------------------------------------------------------------------

extern "C" void kernel_launch(void* const* d_in, const int* in_sizes, int n_in,
                              void* d_out, int out_size, void* d_ws, size_t ws_size,
                              hipStream_t stream) {
    const float* x0       = (const float*)d_in[0];
    const int*   node_idx = (const int*)d_in[1];
    const int*   edge_idx = (const int*)d_in[2];
    const float* W        = (const float*)d_in[3];
    const float* b        = (const float*)d_in[4];
    float* out = (float*)d_out;
    float* x1  = out + (size_t)N_NODES * C;   // output 1

    char* p = (char*)d_ws;
    size_t used = 0;
    auto alloc = [&](size_t bytes) {
        char* r = p + used;
        used += (bytes + 255) & ~(size_t)255;
        return r;
    };
    int* off_e   = (int*)alloc((N_EDGES + 1) * 4);
    int* off_n   = (int*)alloc((N_NODES + 1) * 4);
    int* gcnt_e  = (int*)alloc(NBC_E * 4);    // gcnt_e/gcnt_n adjacent: single memset
    int* gcnt_n  = (int*)alloc(NBC_N * 4);
    int* gbase_e = (int*)alloc((NBC_E + 1) * 4);
    int* gbase_n = (int*)alloc((NBC_N + 1) * 4);
    int* gcur_e  = (int*)alloc(NBC_E * 4);
    int* gcur_n  = (int*)alloc(NBC_N * 4);
    int* perm_e  = (int*)alloc((size_t)NNZ * 4);
    int* perm_n  = (int*)alloc((size_t)NNZ * 4);
    unsigned short* Wb  = (unsigned short*)alloc((size_t)2 * 4096 * 8 * 2);
    unsigned short* x0b = (unsigned short*)alloc((size_t)N_NODES * C * 2);
    unsigned short* x1b = (unsigned short*)alloc((size_t)N_EDGES * C * 2);
    unsigned short* xm  = (unsigned short*)alloc((size_t)N_NODES * C * 2);

    if (ws_size < used) {
        long long tot4 = (long long)(N_NODES + N_EDGES) * C / 4;
        init_kernel<<<(int)((tot4 + 255) / 256), 256, 0, stream>>>(x0, out);
        int grid = NNZ / 4;
        scatter_add_kernel<<<grid, 256, 0, stream>>>(x0, node_idx, edge_idx, x1);
        scatter_add_kernel<<<grid, 256, 0, stream>>>(x1, edge_idx, node_idx, out);
        gin_gemm_kernel<<<N_NODES, 256, 0, stream>>>(W, b, out);
        return;
    }

    // zero the adjacent gcnt_e | gcnt_n region (1.6 KB)
    hipMemsetAsync(gcnt_e, 0, (size_t)((char*)gcnt_n - (char*)gcnt_e) + (size_t)NBC_N * 4, stream);

    // fused x0->bf16 conversion + coarse histogram
    convert_hist<<<CONV_BLOCKS + NCHUNK, 256, 0, stream>>>(x0, x0b, node_idx, edge_idx,
                                                           gcnt_e, gcnt_n);

    // W -> pre-swizzled bf16 (once)
    prep_w<<<32, 256, 0, stream>>>(W, Wb);

    // coarse exclusive scan -> bucket region bases + working cursors
    coarse_scan<<<2, 256, 0, stream>>>(gcnt_e, gcnt_n, gbase_e, gbase_n, gcur_e, gcur_n);

    // permutation build: counting-sort partition (no per-entry global atomics).
    // tmp arrays alias x1b/xm: both are dead until pull_edge/pull_node, which
    // run strictly after scatter_fine consumed tmp (same stream).
    unsigned int* tmp_e = (unsigned int*)x1b;
    unsigned int* tmp_n = (unsigned int*)xm;
    bin_coarse<<<NCHUNK, 256, 0, stream>>>(node_idx, edge_idx, gcur_e, gcur_n, tmp_e, tmp_n);
    // scatter_fine also builds off[] (per-bucket LDS histogram + scan)
    scatter_fine<<<NBC_E + NBC_N, 256, 0, stream>>>(tmp_e, tmp_n, gbase_e, gbase_n,
                                                    off_e, off_n, perm_e, perm_n);

    // pulls
    pull_edge<<<N_EDGES / 4, 256, 0, stream>>>(x0b, off_e, perm_e, x1, x1b);
    pull_node<<<N_NODES / 4, 256, 0, stream>>>(x0, x1b, off_n, perm_n, xm);

    // GEMM: out0 = xm @ W^T + b
    const int row_tiles = (N_NODES + 127) / 128;   // 782
    mfma_gemm2<<<row_tiles * 2, 512, 0, stream>>>(xm, Wb, b, out);
}

// Round 5
// 432.161 us; speedup vs baseline: 1.8651x; 1.0474x over previous
//
#include <hip/hip_runtime.h>

#define N_NODES 100000
#define N_EDGES 50000
#define NNZ     800000
#define C       256

// coarse-bucket counting sort: bucket = contiguous key range.
#define SHC_E 8                                        // 256 edges / bucket
#define SHC_N 9                                        // 512 nodes / bucket
#define NBC_E ((N_EDGES + (1 << SHC_E) - 1) >> SHC_E)  // 196
#define NBC_N ((N_NODES + (1 << SHC_N) - 1) >> SHC_N)  // 196
#define CHUNK 4096
#define NCHUNK ((NNZ + CHUNK - 1) / CHUNK)             // 196

#define CONV_BLOCKS (N_NODES * C / 4 / 256)            // 25600
#define PREPW_BLOCKS 32

typedef short  bf16x8 __attribute__((ext_vector_type(8)));
typedef float  f32x4  __attribute__((ext_vector_type(4)));

static __device__ __forceinline__ unsigned short f2bf(float f) {
    unsigned int u = __float_as_uint(f);
    u += 0x7FFF + ((u >> 16) & 1);   // round-to-nearest-even
    return (unsigned short)(u >> 16);
}
static __device__ __forceinline__ float bf2f(unsigned short u) {
    return __uint_as_float(((unsigned int)u) << 16);
}

// ------- fused x0->bf16 conversion + coarse histogram (persisted) + prep_w ---
// Histogram blocks keep their per-chunk LDS histograms AND write them to
// chunkhist so bin_coarse can skip rebuilding them (saves a full idx pass).

__global__ void convert_hist(const float* __restrict__ x0, unsigned short* __restrict__ x0b,
                             const int* __restrict__ node_idx, const int* __restrict__ edge_idx,
                             int* __restrict__ gcnt_e, int* __restrict__ gcnt_n,
                             int* __restrict__ chunkhist_e, int* __restrict__ chunkhist_n,
                             const float* __restrict__ W, unsigned short* __restrict__ Wb) {
    int bid = blockIdx.x;
    if (bid < CONV_BLOCKS) {
        size_t i = (size_t)bid * 256 + threadIdx.x;   // float4 index
        float4 v = ((const float4*)x0)[i];
        ushort4 o;
        o.x = f2bf(v.x); o.y = f2bf(v.y); o.z = f2bf(v.z); o.w = f2bf(v.w);
        ((ushort4*)x0b)[i] = o;
    } else if (bid < CONV_BLOCKS + NCHUNK) {
        __shared__ int he[NBC_E], hn[NBC_N];
        const int tid = threadIdx.x;
        const int chunk = bid - CONV_BLOCKS;
        for (int i = tid; i < NBC_E; i += 256) he[i] = 0;
        for (int i = tid; i < NBC_N; i += 256) hn[i] = 0;
        __syncthreads();
        const int start = chunk * CHUNK;
        const int end = (start + CHUNK < NNZ) ? start + CHUNK : NNZ;
        for (int k = start + tid; k < end; k += 256) {
            atomicAdd(&he[edge_idx[k] >> SHC_E], 1);
            atomicAdd(&hn[node_idx[k] >> SHC_N], 1);
        }
        __syncthreads();
        for (int i = tid; i < NBC_E; i += 256) {
            int c = he[i];
            chunkhist_e[chunk * NBC_E + i] = c;
            if (c) atomicAdd(&gcnt_e[i], c);
        }
        for (int i = tid; i < NBC_N; i += 256) {
            int c = hn[i];
            chunkhist_n[chunk * NBC_N + i] = c;
            if (c) atomicAdd(&gcnt_n[i], c);
        }
    } else {
        // prep_w: W -> bf16, pre-swizzled to the GEMM's LDS layout
        int idx = (bid - CONV_BLOCKS - NCHUNK) * 256 + threadIdx.x;   // 0..8191
        int h = idx >> 12, i = idx & 4095;
        int t = i >> 9, s = (i >> 6) & 7, l = i & 63;
        int m = l & 15, q = l >> 4;
        const float* src = W + (size_t)(h * 128 + 16 * t + m) * C + 32 * s + 8 * q;
        float4 f0 = *(const float4*)(src);
        float4 f1 = *(const float4*)(src + 4);
        unsigned short* d = Wb + (size_t)idx * 8;
        d[0] = f2bf(f0.x); d[1] = f2bf(f0.y); d[2] = f2bf(f0.z); d[3] = f2bf(f0.w);
        d[4] = f2bf(f1.x); d[5] = f2bf(f1.y); d[6] = f2bf(f1.z); d[7] = f2bf(f1.w);
    }
}

// ------------- coarse exclusive scan: gcnt -> gbase (regions) + gcur ---------

__global__ void coarse_scan(const int* __restrict__ gcnt_e, const int* __restrict__ gcnt_n,
                            int* __restrict__ gbase_e, int* __restrict__ gbase_n,
                            int* __restrict__ gcur_e, int* __restrict__ gcur_n) {
    const int* gcnt = (blockIdx.x == 0) ? gcnt_e : gcnt_n;
    int* gbase = (blockIdx.x == 0) ? gbase_e : gbase_n;
    int* gcur  = (blockIdx.x == 0) ? gcur_e : gcur_n;
    const int nb = (blockIdx.x == 0) ? NBC_E : NBC_N;
    int tid = threadIdx.x, lane = tid & 63, wid = tid >> 6;
    int v = (tid < nb) ? gcnt[tid] : 0;
    int incl = v;
#pragma unroll
    for (int s = 1; s < 64; s <<= 1) { int u = __shfl_up(incl, s, 64); if (lane >= s) incl += u; }
    __shared__ int wsum[4];
    if (lane == 63) wsum[wid] = incl;
    __syncthreads();
    int add = 0;
    for (int i = 0; i < wid; i++) add += wsum[i];
    int excl = add + incl - v;
    if (tid <= nb) gbase[tid] = excl;        // gbase[nb] = NNZ
    if (tid < nb)  gcur[tid]  = excl;
}

// ---------------- permutation build: counting-sort partition ----------------
// Phase B (bin_coarse): loads the persisted per-chunk histogram, ONE global
//   atomic per (block,bucket) to reserve a contiguous region, LDS-cursor scatter.

__global__ __launch_bounds__(256) void bin_coarse(const int* __restrict__ node_idx,
                                                  const int* __restrict__ edge_idx,
                                                  int* __restrict__ gcur_e, int* __restrict__ gcur_n,
                                                  const int* __restrict__ chunkhist_e,
                                                  const int* __restrict__ chunkhist_n,
                                                  unsigned int* __restrict__ tmp_e,
                                                  unsigned int* __restrict__ tmp_n) {
    __shared__ int hist_e[NBC_E], hist_n[NBC_N];
    __shared__ int base_e[NBC_E], base_n[NBC_N];
    const int tid = threadIdx.x;
    const int chunk = blockIdx.x;
    const int start = chunk * CHUNK;
    const int end = (start + CHUNK < NNZ) ? start + CHUNK : NNZ;

    for (int i = tid; i < NBC_E; i += 256) {
        int c = chunkhist_e[chunk * NBC_E + i];
        base_e[i] = c ? atomicAdd(&gcur_e[i], c) : 0;
        hist_e[i] = 0;
    }
    for (int i = tid; i < NBC_N; i += 256) {
        int c = chunkhist_n[chunk * NBC_N + i];
        base_n[i] = c ? atomicAdd(&gcur_n[i], c) : 0;
        hist_n[i] = 0;
    }
    __syncthreads();

    for (int k = start + tid; k < end; k += 256) {
        int ni = node_idx[k], ei = edge_idx[k];
        int be = ei >> SHC_E;
        int pe = base_e[be] + atomicAdd(&hist_e[be], 1);
        tmp_e[pe] = ((unsigned int)ni << SHC_E) | (unsigned int)(ei & ((1 << SHC_E) - 1));
        int bn = ni >> SHC_N;
        int pn = base_n[bn] + atomicAdd(&hist_n[bn], 1);
        tmp_n[pn] = ((unsigned int)ei << SHC_N) | (unsigned int)(ni & ((1 << SHC_N) - 1));
    }
}

// Phase C (scatter_fine): per coarse bucket — LDS fine histogram + scan,
// writes the off[] slice, scatters perm into the bucket's contiguous window.

template <int SHC, int NTOT>
static __device__ __forceinline__ void scatter_fine_body(const unsigned int* __restrict__ tmp,
                                                         const int* __restrict__ gbase,
                                                         int* __restrict__ off,
                                                         int* __restrict__ perm,
                                                         int b, int* hist, int* cur, int* wsum) {
    constexpr int NK = 1 << SHC;
    const int tid = threadIdx.x, lane = tid & 63, wid = tid >> 6;
    const int start = gbase[b], end = gbase[b + 1];
    for (int t = tid; t < NK; t += 256) hist[t] = 0;
    __syncthreads();
    for (int k = start + tid; k < end; k += 256)
        atomicAdd(&hist[tmp[k] & (NK - 1)], 1);
    __syncthreads();
    int v0, v1 = 0, local;
    if constexpr (NK == 512) { v0 = hist[2 * tid]; v1 = hist[2 * tid + 1]; local = v0 + v1; }
    else                     { v0 = hist[tid]; local = v0; }
    int incl = local;
#pragma unroll
    for (int s = 1; s < 64; s <<= 1) { int u = __shfl_up(incl, s, 64); if (lane >= s) incl += u; }
    if (lane == 63) wsum[wid] = incl;
    __syncthreads();
    int add = 0;
    for (int i = 0; i < wid; i++) add += wsum[i];
    int base = start + add + incl - local;   // absolute exclusive position
    const int kbase = b << SHC;
    if constexpr (NK == 512) {
        int key0 = kbase + 2 * tid;
        if (key0 < NTOT)     off[key0] = base;
        if (key0 + 1 < NTOT) off[key0 + 1] = base + v0;
        cur[2 * tid]     = base;
        cur[2 * tid + 1] = base + v0;
    } else {
        int key0 = kbase + tid;
        if (key0 < NTOT) off[key0] = base;
        cur[tid] = base;
    }
    if (b == ((NTOT - 1) >> SHC) && tid == 0) off[NTOT] = end;   // = NNZ
    __syncthreads();
    for (int k = start + tid; k < end; k += 256) {
        unsigned int u = tmp[k];
        int pos = atomicAdd(&cur[u & (NK - 1)], 1);
        perm[pos] = (int)(u >> SHC);
    }
}

__global__ __launch_bounds__(256) void scatter_fine(const unsigned int* __restrict__ tmp_e,
                                                    const unsigned int* __restrict__ tmp_n,
                                                    const int* __restrict__ gbase_e,
                                                    const int* __restrict__ gbase_n,
                                                    int* __restrict__ off_e, int* __restrict__ off_n,
                                                    int* __restrict__ perm_e, int* __restrict__ perm_n) {
    __shared__ int hist[1 << SHC_N], cur[1 << SHC_N], wsum[4];
    if (blockIdx.x < NBC_E)
        scatter_fine_body<SHC_E, N_EDGES>(tmp_e, gbase_e, off_e, perm_e, blockIdx.x, hist, cur, wsum);
    else
        scatter_fine_body<SHC_N, N_NODES>(tmp_n, gbase_n, off_n, perm_n, blockIdx.x - NBC_E, hist, cur, wsum);
}

// ---------------- segment-sum pulls: pair-gather ----------------------------
// Wave of 64 lanes: lo half (lanes 0-31) handles even rows, hi half odd rows;
// each lane loads 16 B (8 ch). 8 rows in flight per unrolled step, half the
// load instructions of the old scheme. Halves combined via shfl at the end.

__global__ void pull_edge(const unsigned short* __restrict__ x0b,
                          const int* __restrict__ off, const int* __restrict__ perm,
                          float* __restrict__ x1, unsigned short* __restrict__ x1b) {
    int e = blockIdx.x * 4 + (threadIdx.x >> 6);
    int lane = threadIdx.x & 63;
    int half = lane >> 5;
    int cl = lane & 31;
    int s0 = off[e], s1 = off[e + 1];
    float a[8] = {0, 0, 0, 0, 0, 0, 0, 0};
    float b[8] = {0, 0, 0, 0, 0, 0, 0, 0};
    int k = s0;
    for (; k + 8 <= s1; k += 8) {
        int r0 = perm[k + half],     r1 = perm[k + 2 + half];
        int r2 = perm[k + 4 + half], r3 = perm[k + 6 + half];
        bf16x8 u0 = *(const bf16x8*)(x0b + (size_t)r0 * C + cl * 8);
        bf16x8 u1 = *(const bf16x8*)(x0b + (size_t)r1 * C + cl * 8);
        bf16x8 u2 = *(const bf16x8*)(x0b + (size_t)r2 * C + cl * 8);
        bf16x8 u3 = *(const bf16x8*)(x0b + (size_t)r3 * C + cl * 8);
#pragma unroll
        for (int j = 0; j < 8; j++) {
            a[j] += bf2f((unsigned short)u0[j]); b[j] += bf2f((unsigned short)u1[j]);
            a[j] += bf2f((unsigned short)u2[j]); b[j] += bf2f((unsigned short)u3[j]);
        }
    }
    for (; k + 2 <= s1; k += 2) {
        int r = perm[k + half];
        bf16x8 u = *(const bf16x8*)(x0b + (size_t)r * C + cl * 8);
#pragma unroll
        for (int j = 0; j < 8; j++) a[j] += bf2f((unsigned short)u[j]);
    }
    if (k < s1 && half == 0) {   // single leftover row: lo half only
        int r = perm[k];
        bf16x8 u = *(const bf16x8*)(x0b + (size_t)r * C + cl * 8);
#pragma unroll
        for (int j = 0; j < 8; j++) a[j] += bf2f((unsigned short)u[j]);
    }
#pragma unroll
    for (int j = 0; j < 8; j++) a[j] += b[j];
#pragma unroll
    for (int j = 0; j < 8; j++) a[j] += __shfl_down(a[j], 32);
    if (half == 0) {
        f32x4 vlo = {a[0], a[1], a[2], a[3]};
        f32x4 vhi = {a[4], a[5], a[6], a[7]};
        __builtin_nontemporal_store(vlo, (f32x4*)(x1 + (size_t)e * C + cl * 8));
        __builtin_nontemporal_store(vhi, (f32x4*)(x1 + (size_t)e * C + cl * 8 + 4));
        bf16x8 o;
#pragma unroll
        for (int j = 0; j < 8; j++) o[j] = (short)f2bf(a[j]);
        *(bf16x8*)(x1b + (size_t)e * C + cl * 8) = o;
    }
}

__global__ void pull_node(const unsigned short* __restrict__ x0b,
                          const unsigned short* __restrict__ x1b,
                          const int* __restrict__ off, const int* __restrict__ perm,
                          unsigned short* __restrict__ xm) {
    int n = blockIdx.x * 4 + (threadIdx.x >> 6);
    int lane = threadIdx.x & 63;
    int half = lane >> 5;
    int cl = lane & 31;
    int s0 = off[n], s1 = off[n + 1];
    float a[8] = {0, 0, 0, 0, 0, 0, 0, 0};
    float b[8] = {0, 0, 0, 0, 0, 0, 0, 0};
    int k = s0;
    for (; k + 8 <= s1; k += 8) {
        int r0 = perm[k + half],     r1 = perm[k + 2 + half];
        int r2 = perm[k + 4 + half], r3 = perm[k + 6 + half];
        bf16x8 u0 = *(const bf16x8*)(x1b + (size_t)r0 * C + cl * 8);
        bf16x8 u1 = *(const bf16x8*)(x1b + (size_t)r1 * C + cl * 8);
        bf16x8 u2 = *(const bf16x8*)(x1b + (size_t)r2 * C + cl * 8);
        bf16x8 u3 = *(const bf16x8*)(x1b + (size_t)r3 * C + cl * 8);
#pragma unroll
        for (int j = 0; j < 8; j++) {
            a[j] += bf2f((unsigned short)u0[j]); b[j] += bf2f((unsigned short)u1[j]);
            a[j] += bf2f((unsigned short)u2[j]); b[j] += bf2f((unsigned short)u3[j]);
        }
    }
    for (; k + 2 <= s1; k += 2) {
        int r = perm[k + half];
        bf16x8 u = *(const bf16x8*)(x1b + (size_t)r * C + cl * 8);
#pragma unroll
        for (int j = 0; j < 8; j++) a[j] += bf2f((unsigned short)u[j]);
    }
    if (k < s1 && half == 0) {
        int r = perm[k];
        bf16x8 u = *(const bf16x8*)(x1b + (size_t)r * C + cl * 8);
#pragma unroll
        for (int j = 0; j < 8; j++) a[j] += bf2f((unsigned short)u[j]);
    }
#pragma unroll
    for (int j = 0; j < 8; j++) a[j] += b[j];
#pragma unroll
    for (int j = 0; j < 8; j++) a[j] += __shfl_down(a[j], 32);
    if (half == 0) {
        bf16x8 xr = *(const bf16x8*)(x0b + (size_t)n * C + cl * 8);
        bf16x8 o;
#pragma unroll
        for (int j = 0; j < 8; j++) o[j] = (short)f2bf(a[j] + bf2f((unsigned short)xr[j]));
        *(bf16x8*)(xm + (size_t)n * C + cl * 8) = o;
    }
}

// ---------------- MFMA GEMM: pre-swizzled bf16 W-half staged in 64 KB LDS ----

__global__ __launch_bounds__(512) void mfma_gemm2(const unsigned short* __restrict__ xm,
                                                  const unsigned short* __restrict__ Wb,
                                                  const float* __restrict__ bias,
                                                  float* __restrict__ out) {
    __shared__ unsigned short Bs[8 * 8 * 64 * 8];   // 65536 B
    const int rt = blockIdx.x >> 1;
    const int colbase = (blockIdx.x & 1) * 128;
    const int tid = threadIdx.x;

    const unsigned short* wsrc = Wb + (size_t)(blockIdx.x & 1) * (4096 * 8);
#pragma unroll
    for (int it = 0; it < 8; it++) {
        int i = it * 512 + tid;
        *(bf16x8*)(Bs + (size_t)i * 8) = *(const bf16x8*)(wsrc + (size_t)i * 8);
    }

    const int w = tid >> 6, lane = tid & 63;
    const int m = lane & 15, q = lane >> 4;
    const int row = rt * 128 + w * 16 + m;
    const int arow = row < N_NODES ? row : N_NODES - 1;   // clamp tail (stores guarded)

    bf16x8 a[8];
    const unsigned short* ap = xm + (size_t)arow * C + q * 8;
#pragma unroll
    for (int s = 0; s < 8; s++) a[s] = *(const bf16x8*)(ap + 32 * s);

    __syncthreads();

    f32x4 acc[8];
#pragma unroll
    for (int t = 0; t < 8; t++) acc[t] = (f32x4){0.f, 0.f, 0.f, 0.f};

#pragma unroll
    for (int s = 0; s < 8; s++) {
#pragma unroll
        for (int t = 0; t < 8; t++) {
            bf16x8 b = *(const bf16x8*)(Bs + ((t * 8 + s) * 64 + lane) * 8);
            acc[t] = __builtin_amdgcn_mfma_f32_16x16x32_bf16(a[s], b, acc[t], 0, 0, 0);
        }
    }

    const int r0 = rt * 128 + w * 16 + q * 4;
#pragma unroll
    for (int t = 0; t < 8; t++) {
        float bv = bias[colbase + t * 16 + m];
#pragma unroll
        for (int r = 0; r < 4; r++) {
            int rr = r0 + r;
            if (rr < N_NODES)
                __builtin_nontemporal_store(acc[t][r] + bv,
                                            out + (size_t)rr * C + colbase + t * 16 + m);
        }
    }
}

// ---------------- fallback (round-1 path, used only if ws too small) --------

__global__ void init_kernel(const float* __restrict__ x0, float* __restrict__ out) {
    long long i = (long long)blockIdx.x * blockDim.x + threadIdx.x;
    const long long n_node4 = (long long)N_NODES * C / 4;
    const long long n_tot4  = (long long)(N_NODES + N_EDGES) * C / 4;
    float4* o4 = (float4*)out;
    if (i < n_node4)      o4[i] = ((const float4*)x0)[i];
    else if (i < n_tot4)  o4[i] = make_float4(0.f, 0.f, 0.f, 0.f);
}

__global__ void scatter_add_kernel(const float* __restrict__ src,
                                   const int* __restrict__ src_idx,
                                   const int* __restrict__ dst_idx,
                                   float* __restrict__ dst) {
    int j    = blockIdx.x * (blockDim.x >> 6) + (threadIdx.x >> 6);
    int lane = threadIdx.x & 63;
    if (j >= NNZ) return;
    int s = src_idx[j];
    int d = dst_idx[j];
    const float4 v = *(const float4*)(src + (long long)s * C + lane * 4);
    float* dp = dst + (long long)d * C + lane * 4;
    atomicAdd(dp + 0, v.x); atomicAdd(dp + 1, v.y);
    atomicAdd(dp + 2, v.z); atomicAdd(dp + 3, v.w);
}

__global__ void gin_gemm_kernel(const float* __restrict__ W,
                                const float* __restrict__ b,
                                float* __restrict__ out) {
    int n = blockIdx.x;
    int t = threadIdx.x;
    __shared__ float xs[C];
    float* row = out + (long long)n * C;
    xs[t] = row[t];
    __syncthreads();
    float acc = b[t];
    const float* wrow = W + t * C;
#pragma unroll 8
    for (int k = 0; k < C; k += 4) {
        float4 xv = *(const float4*)(xs + k);
        float4 wv = *(const float4*)(wrow + k);
        acc = fmaf(xv.x, wv.x, acc); acc = fmaf(xv.y, wv.y, acc);
        acc = fmaf(xv.z, wv.z, acc); acc = fmaf(xv.w, wv.w, acc);
    }
    row[t] = acc;
}

// ---------------------------------------------------------------------------

extern "C" void kernel_launch(void* const* d_in, const int* in_sizes, int n_in,
                              void* d_out, int out_size, void* d_ws, size_t ws_size,
                              hipStream_t stream) {
    const float* x0       = (const float*)d_in[0];
    const int*   node_idx = (const int*)d_in[1];
    const int*   edge_idx = (const int*)d_in[2];
    const float* W        = (const float*)d_in[3];
    const float* b        = (const float*)d_in[4];
    float* out = (float*)d_out;
    float* x1  = out + (size_t)N_NODES * C;   // output 1

    char* p = (char*)d_ws;
    size_t used = 0;
    auto alloc = [&](size_t bytes) {
        char* r = p + used;
        used += (bytes + 255) & ~(size_t)255;
        return r;
    };
    int* off_e   = (int*)alloc((N_EDGES + 1) * 4);
    int* off_n   = (int*)alloc((N_NODES + 1) * 4);
    int* gcnt_e  = (int*)alloc(NBC_E * 4);    // gcnt_e/gcnt_n adjacent: single memset
    int* gcnt_n  = (int*)alloc(NBC_N * 4);
    int* gbase_e = (int*)alloc((NBC_E + 1) * 4);
    int* gbase_n = (int*)alloc((NBC_N + 1) * 4);
    int* gcur_e  = (int*)alloc(NBC_E * 4);
    int* gcur_n  = (int*)alloc(NBC_N * 4);
    int* chunkhist_e = (int*)alloc((size_t)NCHUNK * NBC_E * 4);
    int* chunkhist_n = (int*)alloc((size_t)NCHUNK * NBC_N * 4);
    int* perm_e  = (int*)alloc((size_t)NNZ * 4);
    int* perm_n  = (int*)alloc((size_t)NNZ * 4);
    unsigned short* Wb  = (unsigned short*)alloc((size_t)2 * 4096 * 8 * 2);
    unsigned short* x0b = (unsigned short*)alloc((size_t)N_NODES * C * 2);
    unsigned short* x1b = (unsigned short*)alloc((size_t)N_EDGES * C * 2);
    unsigned short* xm  = (unsigned short*)alloc((size_t)N_NODES * C * 2);

    if (ws_size < used) {
        long long tot4 = (long long)(N_NODES + N_EDGES) * C / 4;
        init_kernel<<<(int)((tot4 + 255) / 256), 256, 0, stream>>>(x0, out);
        int grid = NNZ / 4;
        scatter_add_kernel<<<grid, 256, 0, stream>>>(x0, node_idx, edge_idx, x1);
        scatter_add_kernel<<<grid, 256, 0, stream>>>(x1, edge_idx, node_idx, out);
        gin_gemm_kernel<<<N_NODES, 256, 0, stream>>>(W, b, out);
        return;
    }

    // zero the adjacent gcnt_e | gcnt_n region (1.6 KB)
    hipMemsetAsync(gcnt_e, 0, (size_t)((char*)gcnt_n - (char*)gcnt_e) + (size_t)NBC_N * 4, stream);

    // fused x0->bf16 conversion + coarse histogram (persisted) + prep_w
    convert_hist<<<CONV_BLOCKS + NCHUNK + PREPW_BLOCKS, 256, 0, stream>>>(
        x0, x0b, node_idx, edge_idx, gcnt_e, gcnt_n, chunkhist_e, chunkhist_n, W, Wb);

    // coarse exclusive scan -> bucket region bases + working cursors
    coarse_scan<<<2, 256, 0, stream>>>(gcnt_e, gcnt_n, gbase_e, gbase_n, gcur_e, gcur_n);

    // permutation build: counting-sort partition (no per-entry global atomics).
    // tmp arrays alias x1b/xm: both are dead until pull_edge/pull_node, which
    // run strictly after scatter_fine consumed tmp (same stream).
    unsigned int* tmp_e = (unsigned int*)x1b;
    unsigned int* tmp_n = (unsigned int*)xm;
    bin_coarse<<<NCHUNK, 256, 0, stream>>>(node_idx, edge_idx, gcur_e, gcur_n,
                                           chunkhist_e, chunkhist_n, tmp_e, tmp_n);
    // scatter_fine also builds off[] (per-bucket LDS histogram + scan)
    scatter_fine<<<NBC_E + NBC_N, 256, 0, stream>>>(tmp_e, tmp_n, gbase_e, gbase_n,
                                                    off_e, off_n, perm_e, perm_n);

    // pulls (pair-gather)
    pull_edge<<<N_EDGES / 4, 256, 0, stream>>>(x0b, off_e, perm_e, x1, x1b);
    pull_node<<<N_NODES / 4, 256, 0, stream>>>(x0b, x1b, off_n, perm_n, xm);

    // GEMM: out0 = xm @ W^T + b
    const int row_tiles = (N_NODES + 127) / 128;   // 782
    mfma_gemm2<<<row_tiles * 2, 512, 0, stream>>>(xm, Wb, b, out);
}